// Round 4
// baseline (331.774 us; speedup 1.0000x reference)
//
#include <hip/hip_runtime.h>
#include <math.h>

#define NB 8
#define NC 192
#define NH 56
#define NW 56
#define NN 3136      // NH*NW
#define NK 16        // clusters
#define KNB 9        // neighbors
#define NCOUT 384    // 2*NC
#define LPMAX 320    // max padded cluster size (L~196±14, 320 is >8 sigma)
#define DSTRIDE 320
#define DSLOT (320 * 320)

#define FLT_INF __builtin_inff()

typedef short s16x8 __attribute__((ext_vector_type(8)));
typedef _Float16 f16x8 __attribute__((ext_vector_type(8)));
typedef float f32x4 __attribute__((ext_vector_type(4)));
typedef unsigned short us8 __attribute__((ext_vector_type(8)));
typedef unsigned short us4 __attribute__((ext_vector_type(4)));

// gelu(tanh approx) via exact sigmoid identity: 0.5*(1+tanh(u)) = 1/(1+exp(-2u)).
__device__ __forceinline__ float gelu_t(float x) {
    const float k0 = 0.7978845608028654f;
    float u = k0 * (x + 0.044715f * x * x * x);
    float sg = __builtin_amdgcn_rcpf(1.0f + __expf(-2.0f * u));
    return x * sg;
}

__device__ __forceinline__ unsigned short f2bf(float f) {
    unsigned u = __float_as_uint(f);
    u += 0x7fff + ((u >> 16) & 1);  // round-to-nearest-even
    return (unsigned short)(u >> 16);
}

__device__ __forceinline__ float bf2f(unsigned short h) {
    return __uint_as_float(((unsigned)h) << 16);
}

// ============================================================================
// XCD batch-affinity (T1, batch-per-XCD): lin%8 = batch pins batch b's whole
// pipeline to XCD b; producer->consumer intermediates stay in its 4MiB L2.
// LESSON (R3): do NOT fuse latency-bound gather phases into compute-tile-shaped
// kernels — the 64-row GEMM tile forced 392 blocks and killed the TLP that was
// hiding hv's 9-neighbor gather latency (71µs, 15% occupancy). Gather kernels
// keep their own wide grids.
// ============================================================================

// ---------------- fused front kernel: conv (blocks 0..1535) | order | wcvt
#define FRONT_CONV_BLOCKS (NB * NC)            // 1536
#define FRONT_ORDER_BLOCKS (NB * NK)           // 128
#define FRONT_WCVT_BLOCKS 288                  // 6*12*4
__global__ __launch_bounds__(256) void front_kernel(
    const float* __restrict__ X, const float* __restrict__ W7, const float* __restrict__ bias,
    unsigned short* __restrict__ xpe,
    const int* __restrict__ labels, int* __restrict__ order, int* __restrict__ mapping,
    int* __restrict__ lsv, int* __restrict__ cntk, int* __restrict__ offk,
    const float* __restrict__ Wf1, const float* __restrict__ Wv, const float* __restrict__ Wf2,
    unsigned short* __restrict__ wf1, unsigned short* __restrict__ wfpmq,
    unsigned short* __restrict__ wfq, unsigned short* __restrict__ wf2) {
    __shared__ float tile[62 * 62];
    __shared__ float wl[49];
    int bid = blockIdx.x;
    int tid = threadIdx.x;
    if (bid < FRONT_CONV_BLOCKS) {
        // -------- depthwise 7x7 conv + bias + residual -> bf16 xpe --------
        int bc = (bid & 7) * NC + (bid >> 3);  // XCD remap: batch = bid%8
        int c = bc % NC;
        const float* Xp = X + (size_t)bc * NN;
        if (tid < 49) wl[tid] = W7[(size_t)c * 49 + tid];
        for (int idx = tid; idx < 62 * 62; idx += 256) {
            int ty = idx / 62, tx = idx % 62;
            int gy = ty - 3, gx = tx - 3;
            float v = 0.0f;
            if (gy >= 0 && gy < NH && gx >= 0 && gx < NW) v = Xp[gy * NW + gx];
            tile[idx] = v;
        }
        __syncthreads();
        float cb = bias[c];
        for (int g = tid; g < (NN / 4); g += 256) {
            int y = g / (NW / 4), x0 = (g % (NW / 4)) * 4;
            float a0 = 0.f, a1 = 0.f, a2 = 0.f, a3 = 0.f;
#pragma unroll
            for (int dy = 0; dy < 7; ++dy) {
                const float* tr = &tile[(y + dy) * 62 + x0];
#pragma unroll
                for (int dx = 0; dx < 7; ++dx) {
                    float wv = wl[dy * 7 + dx];
                    a0 += tr[dx] * wv;
                    a1 += tr[dx + 1] * wv;
                    a2 += tr[dx + 2] * wv;
                    a3 += tr[dx + 3] * wv;
                }
            }
            const float* rr = &tile[(y + 3) * 62 + x0 + 3];
            us4 o;
            o[0] = f2bf(a0 + cb + rr[0]);
            o[1] = f2bf(a1 + cb + rr[1]);
            o[2] = f2bf(a2 + cb + rr[2]);
            o[3] = f2bf(a3 + cb + rr[3]);
            *(us4*)(xpe + (size_t)bc * NN + y * NW + x0) = o;
        }
    } else if (bid < FRONT_CONV_BLOCKS + FRONT_ORDER_BLOCKS) {
        // -------- stable counting sort (wave 0 only) --------
        if (tid >= 64) return;
        int idx = bid - FRONT_CONV_BLOCKS;
        int b = idx >> 4;
        int k = idx & 15;
        int lane = tid;
        const int* lb = labels + (size_t)b * NN;
        int cntLess = 0, cntEq = 0;
        for (int n0 = 0; n0 < NN; n0 += 64) {
            int lab = lb[n0 + lane] & 15;
            cntLess += __popcll(__ballot(lab < k));
            cntEq += __popcll(__ballot(lab == k));
        }
        int base = cntLess;
        int run = 0;
        for (int n0 = 0; n0 < NN; n0 += 64) {
            int n = n0 + lane;
            int lab = lb[n] & 15;
            bool p = (lab == k);
            unsigned long long mask = __ballot(p);
            int rank = __popcll(mask & ((1ull << lane) - 1ull));
            if (p) {
                int pos = base + run + rank;
                order[b * NN + pos] = n;
                mapping[b * NN + n] = pos;
                lsv[b * NN + pos] = k;
            }
            run += __popcll(mask);
        }
        if (lane == 0) {
            offk[b * NK + k] = base;
            cntk[b * NK + k] = cntEq;
        }
    } else {
        // -------- weight -> B-fragment conversions --------
        int u = bid - (FRONT_CONV_BLOCKS + FRONT_ORDER_BLOCKS);
        int nt = u % 6, kc = (u / 6) % 12, z = u / 72;
        const float* W;
        unsigned short* Bf;
        int ldw, rowoff, KC, NT;
        bool diff = false;
        if (z == 0) { W = Wf1; Bf = wf1; ldw = NC; rowoff = 0; KC = 6; NT = 3; }
        else if (z == 1) { W = Wv; Bf = wfpmq; ldw = NCOUT; rowoff = 0; KC = 6; NT = 6; diff = true; }
        else if (z == 2) { W = Wv; Bf = wfq; ldw = NCOUT; rowoff = NC; KC = 6; NT = 6; }
        else { W = Wf2; Bf = wf2; ldw = NC; rowoff = 0; KC = 12; NT = 3; }
        if (nt >= NT || kc >= KC) return;
        int c = tid >> 6, l = tid & 63;
        int n = l & 15, q = l >> 4;
        int col = nt * 64 + c * 16 + n;
        int krow = rowoff + kc * 32 + q * 8;
        unsigned short pack[8];
#pragma unroll
        for (int j = 0; j < 8; ++j) {
            float v = W[(size_t)(krow + j) * ldw + col];
            if (diff) v -= W[(size_t)(NC + krow + j) * ldw + col];
            pack[j] = f2bf(v);
        }
        *(us8*)(Bf + ((((size_t)nt * KC + kc) * 4 + c) * 64 + l) * 8) = *(const us8*)pack;
    }
}

// ---------------- fc1 fused with transpose: A-fragments built directly from xpe ----------------
// One block per (b, 64-row strip) x ALL 192 cols; A read exactly once. (R3 win: -10µs)
__global__ __launch_bounds__(256) void fc1_kernel(const unsigned short* __restrict__ xpe,
                                                  const unsigned short* __restrict__ Bf,
                                                  const float* __restrict__ bias,
                                                  float* __restrict__ xs,
                                                  unsigned short* __restrict__ Cfrag,
                                                  const int* __restrict__ rowmap) {
    int lin = blockIdx.x;              // 392 = 49*8
    int b = lin & 7, by = lin >> 3;    // XCD remap: batch = lin%8
    int w = threadIdx.x >> 6, lane = threadIdx.x & 63;
    int sg = by * 4 + w;
    int m = lane & 15, q = lane >> 4;
    int n = by * 64 + w * 16 + m;      // spatial row this lane's A-frag covers
    const unsigned short* Xb = xpe + (size_t)b * NC * NN + n;
    f32x4 acc[12] = {};
#pragma unroll
    for (int kc = 0; kc < 6; ++kc) {
        int ch = kc * 32 + q * 8;
        s16x8 a;
#pragma unroll
        for (int j = 0; j < 8; ++j) a[j] = (short)Xb[(size_t)(ch + j) * NN];
#pragma unroll
        for (int ct = 0; ct < 12; ++ct) {
            s16x8 bv = *(const s16x8*)(Bf + ((((size_t)(ct >> 2) * 6 + kc) * 4 + (ct & 3)) * 64 + lane) * 8);
            acc[ct] = __builtin_amdgcn_mfma_f32_16x16x32_bf16(a, bv, acc[ct], 0, 0, 0);
        }
    }
    float* Cb = xs + (size_t)b * NN * NC;
#pragma unroll
    for (int r = 0; r < 4; ++r) {
        int grow = sg * 16 + q * 4 + r;
        int orow = rowmap[(size_t)b * NN + grow];
        int s2 = orow >> 4, m2 = orow & 15;
#pragma unroll
        for (int ct = 0; ct < 12; ++ct) {
            int col = ct * 16 + m;
            float v = acc[ct][r] + bias[col];
            Cb[(size_t)orow * NC + col] = v;
            int kc2 = col >> 5, q2 = (col >> 3) & 3, j2 = col & 7;
            Cfrag[(size_t)b * NN * NC + (((size_t)s2 * 6 + kc2) * 64 + q2 * 16 + m2) * 8 + j2] =
                f2bf(v);
        }
    }
}

// ---------------- merged P/Q GEMM, 2 col-halves: A read 2x (was 6x), 144 MFMA/wave ----------------
__global__ __launch_bounds__(256) void gemm_mfma_pq2(const unsigned short* __restrict__ Af,
                                                     const unsigned short* __restrict__ B1,
                                                     const unsigned short* __restrict__ B2,
                                                     const float* __restrict__ bias,
                                                     unsigned short* __restrict__ PmQ,
                                                     unsigned short* __restrict__ Qh) {
    int lin = blockIdx.x;              // 784 = 2*49*8
    int b = lin & 7, pos = lin >> 3;   // XCD remap: batch = lin%8
    int half = pos & 1, by = pos >> 1;
    int w = threadIdx.x >> 6, lane = threadIdx.x & 63;
    int sg = by * 4 + w;
    const unsigned short* Ap = Af + (size_t)b * NN * NC + ((size_t)sg * 6 * 64 + lane) * 8;
    f32x4 acc1[12] = {};
    f32x4 acc2[12] = {};
#pragma unroll
    for (int kc = 0; kc < 6; ++kc) {
        s16x8 a = *(const s16x8*)(Ap + kc * 512);
#pragma unroll
        for (int ct = 0; ct < 12; ++ct) {
            size_t boff = ((((size_t)(half * 3 + (ct >> 2)) * 6 + kc) * 4 + (ct & 3)) * 64 + lane) * 8;
            s16x8 b1 = *(const s16x8*)(B1 + boff);
            acc1[ct] = __builtin_amdgcn_mfma_f32_16x16x32_bf16(a, b1, acc1[ct], 0, 0, 0);
            s16x8 b2 = *(const s16x8*)(B2 + boff);
            acc2[ct] = __builtin_amdgcn_mfma_f32_16x16x32_bf16(a, b2, acc2[ct], 0, 0, 0);
        }
    }
    int col0 = lane & 15, rq = lane >> 4;
    unsigned short* Pb = PmQ + (size_t)b * NN * NCOUT;
    unsigned short* Qb = Qh + (size_t)b * NN * NCOUT;
#pragma unroll
    for (int r = 0; r < 4; ++r) {
        int grow = sg * 16 + rq * 4 + r;
#pragma unroll
        for (int ct = 0; ct < 12; ++ct) {
            int col = half * 192 + ct * 16 + col0;
            Pb[(size_t)grow * NCOUT + col] = f2bf(acc1[ct][r] + bias[col]);
            Qb[(size_t)grow * NCOUT + col] = f2bf(acc2[ct][r]);
        }
    }
}

// ---------------- xe = xs*rinv -> fp16 A-fragments; computes rinv + sqv in-kernel ----------------
__global__ __launch_bounds__(384) void xe_cvt_kernel(const float* __restrict__ xs,
                                                     const int* __restrict__ offk,
                                                     const int* __restrict__ cntk,
                                                     _Float16* __restrict__ xef,
                                                     float* __restrict__ sqv) {
    __shared__ float psum[16][25];
    __shared__ float rloc[16];
    // grid (20,16,8); XCD remap
    int lin = ((int)blockIdx.z * 16 + blockIdx.y) * 20 + blockIdx.x;
    int b = lin & 7, pos = lin >> 3;
    int k = pos / 20, strip = pos % 20;
    int bk = b * NK + k;
    int base = offk[bk], L = cntk[bk];
    if (strip * 16 >= L) return;
    int kc = threadIdx.x >> 6, l = threadIdx.x & 63;
    int m = l & 15, q = l >> 4;
    int rl = strip * 16 + m;
    int row = base + (rl < L ? rl : L - 1);
    const float* src = xs + ((size_t)b * NN + row) * NC + kc * 32 + q * 8;
    float4 v0 = *(const float4*)src;
    float4 v1 = *(const float4*)(src + 4);
    float part = v0.x * v0.x + v0.y * v0.y + v0.z * v0.z + v0.w * v0.w + v1.x * v1.x +
                 v1.y * v1.y + v1.z * v1.z + v1.w * v1.w;
    psum[m][kc * 4 + q] = part;
    __syncthreads();
    if (threadIdx.x < 16) {
        float s = 0.0f;
#pragma unroll
        for (int i2 = 0; i2 < 24; ++i2) s += psum[threadIdx.x][i2];
        float nrm = fmaxf(sqrtf(s), 1e-12f);
        float ri = 1.0f / nrm;
        rloc[threadIdx.x] = ri;
        if (strip * 16 + (int)threadIdx.x < L)
            sqv[(size_t)b * NN + base + strip * 16 + threadIdx.x] = (s * ri) * ri;
    }
    __syncthreads();
    float rv = rloc[m];
    f16x8 pack;
    pack[0] = (_Float16)(v0.x * rv);
    pack[1] = (_Float16)(v0.y * rv);
    pack[2] = (_Float16)(v0.z * rv);
    pack[3] = (_Float16)(v0.w * rv);
    pack[4] = (_Float16)(v1.x * rv);
    pack[5] = (_Float16)(v1.y * rv);
    pack[6] = (_Float16)(v1.z * rv);
    pack[7] = (_Float16)(v1.w * rv);
    *(f16x8*)(xef + (size_t)bk * (20 * 6 * 512) + (((size_t)strip * 6 + kc) * 64 + l) * 8) =
        pack;
}

// ---------------- Gram -> d2 tiles via fp16 MFMA (stores only live rows/cols) ----------------
__global__ __launch_bounds__(256) void gram_kernel(const _Float16* __restrict__ xef,
                                                   const float* __restrict__ sqv,
                                                   const int* __restrict__ offk,
                                                   const int* __restrict__ cntk,
                                                   float* __restrict__ D) {
    // grid (5,5,128); XCD remap
    int lin = ((int)blockIdx.z * 5 + blockIdx.y) * 5 + blockIdx.x;
    int b = lin & 7, pos = lin >> 3;
    int k = pos / 25, rr = pos % 25;
    int tj = rr / 5, ti = rr % 5;
    int bk = b * NK + k;
    int base = offk[bk], L = cntk[bk];
    if (ti * 64 >= L || tj * 64 >= L) return;
    int w = threadIdx.x >> 6, lane = threadIdx.x & 63;
    const _Float16* Xf = xef + (size_t)bk * (20 * 6 * 512);
    const _Float16* Ap = Xf + (((size_t)(ti * 4 + w) * 6) * 64 + lane) * 8;
    f32x4 acc[4] = {};
#pragma unroll
    for (int kc = 0; kc < 6; ++kc) {
        f16x8 a = *(const f16x8*)(Ap + kc * 512);
#pragma unroll
        for (int js = 0; js < 4; ++js) {
            f16x8 bv = *(const f16x8*)(Xf + (((size_t)(tj * 4 + js) * 6 + kc) * 64 + lane) * 8);
            acc[js] = __builtin_amdgcn_mfma_f32_16x16x32_f16(a, bv, acc[js], 0, 0, 0);
        }
    }
    float* Dr = D + (size_t)bk * DSLOT;
    const float* Sb = sqv + (size_t)b * NN + base;
    int col0 = lane & 15, rq = lane >> 4;
#pragma unroll
    for (int r = 0; r < 4; ++r) {
        int i = ti * 64 + w * 16 + rq * 4 + r;
        if (i >= L) continue;
        float si = Sb[i];
#pragma unroll
        for (int js = 0; js < 4; ++js) {
            int j = tj * 64 + js * 16 + col0;
            if (j < L) Dr[(size_t)i * DSTRIDE + j] = si + Sb[j] - 2.0f * acc[js][r];
        }
    }
}

// ---------------- top-9 selection: one wave per row (sorted ids) ----------------
#define LEXLT(da, ca, db, cb) ((da) < (db) || ((da) == (db) && (ca) < (cb)))
__global__ __launch_bounds__(256) void select9_kernel(const float* __restrict__ D,
                                                      const int* __restrict__ lsv,
                                                      const int* __restrict__ offk,
                                                      const int* __restrict__ cntk,
                                                      int* __restrict__ nbr) {
    // grid (784,8); XCD remap
    int lin = (int)blockIdx.y * 784 + blockIdx.x;
    int b = lin & 7, quad = lin >> 3;
    int r = quad * 4 + (threadIdx.x >> 6);
    int lane = threadIdx.x & 63;
    int k = lsv[(size_t)b * NN + r];
    int bk = b * NK + k;
    int base = offk[bk], L = cntk[bk];
    int Lc = L < LPMAX ? L : LPMAX;
    const float* Dr = D + (size_t)bk * DSLOT + (size_t)(r - base) * DSTRIDE;
    float d0, d1, d2, d3, d4;
    int c0, c1, c2, c3, c4;
    c0 = lane;
    c1 = lane + 64;
    c2 = lane + 128;
    c3 = lane + 192;
    c4 = lane + 256;
    d0 = c0 < Lc ? Dr[c0] : FLT_INF;
    d1 = c1 < Lc ? Dr[c1] : FLT_INF;
    d2 = c2 < Lc ? Dr[c2] : FLT_INF;
    d3 = c3 < Lc ? Dr[c3] : FLT_INF;
    d4 = c4 < Lc ? Dr[c4] : FLT_INF;
#define CS(da, ca, db, cb)                  \
    if (LEXLT(db, cb, da, ca)) {            \
        float t = da; da = db; db = t;      \
        int u = ca; ca = cb; cb = u;        \
    }
    CS(d0, c0, d1, c1) CS(d3, c3, d4, c4) CS(d2, c2, d4, c4) CS(d2, c2, d3, c3)
    CS(d1, c1, d4, c4) CS(d0, c0, d3, c3) CS(d0, c0, d2, c2) CS(d1, c1, d3, c3)
    CS(d1, c1, d2, c2)
#undef CS
    size_t row = (size_t)b * NN + r;
    for (int q = 0; q < KNB; ++q) {
        float bd = d0;
        int bc = c0;
#pragma unroll
        for (int m = 32; m; m >>= 1) {
            float od = __shfl_xor(bd, m, 64);
            int oc = __shfl_xor(bc, m, 64);
            if (LEXLT(od, oc, bd, bc)) {
                bd = od;
                bc = oc;
            }
        }
        if (lane == 0) nbr[row * KNB + q] = base + bc;
        if (d0 == bd && c0 == bc) {
            d0 = d1; c0 = c1;
            d1 = d2; c1 = c2;
            d2 = d3; c2 = c3;
            d3 = d4; c3 = c4;
            d4 = FLT_INF; c4 = 0x7fffffff;
        }
    }
}

// ---------------- merged centroids + cluster P/Q (one block per bk) ----------------
__global__ __launch_bounds__(768) void cenpq_kernel(const float* __restrict__ xs,
                                                    const int* __restrict__ offk,
                                                    const int* __restrict__ cntk,
                                                    const float* __restrict__ Wc,
                                                    const float* __restrict__ bc,
                                                    float* __restrict__ Pc,
                                                    float* __restrict__ Qc) {
    __shared__ float part[4][NC];
    __shared__ float ce[NC];
    __shared__ float pcs[NCOUT], qcs[NCOUT];
    // XCD remap: bk = (bid%8)*16 + bid/8
    int bk = ((int)blockIdx.x & 7) * NK + ((int)blockIdx.x >> 3);
    int b = bk >> 4;
    int base = offk[bk], L = cntk[bk];
    int w = threadIdx.x / NC;  // 0..3 row partition
    int c = threadIdx.x % NC;
    const float* Xb = xs + ((size_t)b * NN + base) * NC + c;
    float s = 0.0f;
    for (int r = w; r < L; r += 4) s += Xb[(size_t)r * NC];
    part[w][c] = s;
    __syncthreads();
    if (threadIdx.x < NC) {
        int cc = threadIdx.x;
        float tot = part[0][cc] + part[1][cc] + part[2][cc] + part[3][cc];
        ce[cc] = tot / fmaxf((float)L, 1.0f);
    }
    __syncthreads();
    int o = threadIdx.x % NCOUT, half = threadIdx.x / NCOUT;
    float pc = 0.0f, qc = 0.0f;
    int cs = half * 96, cend = cs + 96;
    for (int c2 = cs; c2 < cend; ++c2) {
        float cv = ce[c2];
        pc += cv * Wc[(size_t)c2 * NCOUT + o];
        qc += cv * Wc[(size_t)(NC + c2) * NCOUT + o];
    }
    if (half == 1) {
        pcs[o] = pc;
        qcs[o] = qc;
    }
    __syncthreads();
    if (half == 0) {
        Pc[(size_t)bk * NCOUT + o] = pc + pcs[o] + bc[o];
        Qc[(size_t)bk * NCOUT + o] = qc + qcs[o];
    }
}

// ---------------- cluster message max (valley trick, 128 blocks) ----------------
__global__ __launch_bounds__(384) void hcmax_kernel(const float* __restrict__ Pc,
                                                    const float* __restrict__ Qc,
                                                    float* __restrict__ hc) {
    int bk = ((int)blockIdx.x & 7) * NK + ((int)blockIdx.x >> 3);
    int b = bk >> 4, i = bk & 15;
    int o = threadIdx.x;
    float pi = Pc[((size_t)b * NK + i) * NCOUT + o];
    float qi = Qc[((size_t)b * NK + i) * NCOUT + o];
    float pmq = pi - qi;
    float qmn = FLT_INF, qmx = -FLT_INF;
    for (int j = 0; j < NK; ++j) {
        float v = Qc[((size_t)b * NK + j) * NCOUT + o];
        qmn = fminf(qmn, v);
        qmx = fmaxf(qmx, v);
    }
    hc[((size_t)b * NK + i) * NCOUT + o] =
        fmaxf(gelu_t(pmq + qmn), gelu_t(pmq + qmx));
}

// ---------------- node max + cluster term -> hn bf16 A-fragments (RESTORED: wide-grid gather) ----------------
__global__ __launch_bounds__(192) void hv_kernel(const unsigned short* __restrict__ PmQ,
                                                 const unsigned short* __restrict__ Qh,
                                                 const int* __restrict__ nbr,
                                                 const int* __restrict__ lsv,
                                                 const float* __restrict__ hc,
                                                 unsigned short* __restrict__ hnf) {
    // grid (784,8); XCD remap: b = lin%8 -> gather into Qh[b] is L2-local
    int lin = (int)blockIdx.y * 784 + blockIdx.x;
    int b = lin & 7, quad = lin >> 3;
    int t = threadIdx.x;           // 192 = 4 rows x 48 channel-chunks
    int rsub = t / 48, c = t % 48;
    int i = quad * 4 + rsub;
    size_t row = (size_t)b * NN + i;
    int lab = lsv[row];
    int o0 = c * 8;
    int jn[KNB];
#pragma unroll
    for (int q = 0; q < KNB; ++q) jn[q] = nbr[row * KNB + q];
    const unsigned short* Qbb = Qh + (size_t)b * NN * NCOUT + o0;
    us8 pv = *(const us8*)(PmQ + row * NCOUT + o0);
    us8 q0 = *(const us8*)(Qbb + (size_t)jn[0] * NCOUT);
    float qmn[8], qmx[8];
#pragma unroll
    for (int e = 0; e < 8; ++e) {
        float v = bf2f(q0[e]);
        qmn[e] = v;
        qmx[e] = v;
    }
#pragma unroll
    for (int q = 1; q < KNB; ++q) {
        us8 qv = *(const us8*)(Qbb + (size_t)jn[q] * NCOUT);
#pragma unroll
        for (int e = 0; e < 8; ++e) {
            float v = bf2f(qv[e]);
            qmn[e] = fminf(qmn[e], v);
            qmx[e] = fmaxf(qmx[e], v);
        }
    }
    const float* hcr = hc + ((size_t)b * NK + lab) * NCOUT + o0;
    float4 h0 = *(const float4*)hcr;
    float4 h1 = *(const float4*)(hcr + 4);
    float hcv[8] = {h0.x, h0.y, h0.z, h0.w, h1.x, h1.y, h1.z, h1.w};
    unsigned short pack[8];
#pragma unroll
    for (int e = 0; e < 8; ++e) {
        float pmq = bf2f(pv[e]);
        float m = fmaxf(gelu_t(pmq + qmn[e]), gelu_t(pmq + qmx[e]));
        pack[e] = f2bf(m + hcv[e]);
    }
    int s = i >> 4, mm = i & 15;
    *(us8*)(hnf + (size_t)b * NN * NCOUT +
            (((size_t)s * 12 + (c >> 2)) * 64 + (c & 3) * 16 + mm) * 8) = *(const us8*)pack;
}

// ---------------- fc2: bf16 out + bias, contiguous sorted rows (RESTORED) ----------------
template <int KC>
__global__ __launch_bounds__(256) void gemm_mfma_hb(const unsigned short* __restrict__ Af,
                                                    size_t aStride,
                                                    const unsigned short* __restrict__ Bf,
                                                    const float* __restrict__ bias,
                                                    unsigned short* __restrict__ C,
                                                    size_t cStride, int ldc) {
    // grid (3,49,8); XCD remap
    int lin = ((int)blockIdx.z * 49 + blockIdx.y) * 3 + blockIdx.x;
    int b = lin & 7, pos = lin >> 3;
    int bx = pos % 3, by = pos / 3;
    int w = threadIdx.x >> 6, lane = threadIdx.x & 63;
    int sg = by * 4 + w;
    int n0 = bx * 64;
    const unsigned short* Ap = Af + (size_t)b * aStride + ((size_t)sg * KC * 64 + lane) * 8;
    const unsigned short* Bp = Bf + ((size_t)bx * KC * 256 + lane) * 8;
    f32x4 acc[4] = {};
#pragma unroll
    for (int kc = 0; kc < KC; ++kc) {
        s16x8 a = *(const s16x8*)(Ap + kc * 512);
#pragma unroll
        for (int c = 0; c < 4; ++c) {
            s16x8 bv = *(const s16x8*)(Bp + kc * 2048 + c * 512);
            acc[c] = __builtin_amdgcn_mfma_f32_16x16x32_bf16(a, bv, acc[c], 0, 0, 0);
        }
    }
    int col0 = lane & 15, rq = lane >> 4;
    unsigned short* Cb = C + (size_t)b * cStride;
#pragma unroll
    for (int r = 0; r < 4; ++r) {
        int grow = sg * 16 + rq * 4 + r;
#pragma unroll
        for (int c = 0; c < 4; ++c) {
            int col = n0 + c * 16 + col0;
            Cb[(size_t)grow * ldc + col] = f2bf(acc[c][r] + bias[col]);
        }
    }
}

// ---------------- transpose (b,n,c)->(b,c,n) + residual; row gather via mapping ----------------
__global__ void out_kernel(const unsigned short* __restrict__ T, const float* __restrict__ X,
                           const int* __restrict__ mapping, float* __restrict__ Y) {
    __shared__ float t[32][33];
    // grid (6,98,8); XCD remap
    int lin = ((int)blockIdx.z * 98 + blockIdx.y) * 6 + blockIdx.x;
    int b = lin & 7, pos = lin >> 3;
    int c0 = (pos % 6) * 32, n0 = (pos / 6) * 32;
    int tx = threadIdx.x, ty = threadIdx.y;  // 32 x 8
#pragma unroll
    for (int q = 0; q < 4; ++q) {
        int n = n0 + ty + q * 8;
        int srow = mapping[(size_t)b * NN + n];
        t[ty + q * 8][tx] = bf2f(T[((size_t)b * NN + srow) * NC + c0 + tx]);
    }
    __syncthreads();
#pragma unroll
    for (int q = 0; q < 4; ++q) {
        int c = c0 + ty + q * 8;
        size_t idx = ((size_t)b * NC + c) * NN + n0 + tx;
        Y[idx] = t[tx][ty + q * 8] + X[idx];
    }
}

extern "C" void kernel_launch(void* const* d_in, const int* in_sizes, int n_in, void* d_out,
                              int out_size, void* d_ws, size_t ws_size, hipStream_t stream) {
    const float* x = (const float*)d_in[0];
    const int* labels = (const int*)d_in[1];
    const float* cpe_w = (const float*)d_in[2];
    const float* cpe_b = (const float*)d_in[3];
    const float* fc1_w = (const float*)d_in[4];
    const float* fc1_b = (const float*)d_in[5];
    const float* nn_v_w = (const float*)d_in[6];
    const float* nn_v_b = (const float*)d_in[7];
    const float* nn_c_w = (const float*)d_in[8];
    const float* nn_c_b = (const float*)d_in[9];
    const float* fc2_w = (const float*)d_in[10];
    const float* fc2_b = (const float*)d_in[11];
    float* out = (float*)d_out;

    const size_t SZ_XS = (size_t)NB * NN * NC;
    const size_t SZ_P = (size_t)NB * NN * NCOUT;
    const size_t BN = (size_t)NB * NN;
    const size_t SZ_CEN = (size_t)NB * NK * NC;
    const size_t SZ_PC = (size_t)NB * NK * NCOUT;

    float* base = (float*)d_ws;
    float* xs = base;                 // sorted fc1 out (fp32); reused as bf16 out_t later
    float* xpeRegion = xs + SZ_XS;    // bf16 conv out (ushort)
    float* Pb = xpeRegion + SZ_XS;    // bf16 PmQ (sorted); Dbuf during knn
    float* Qb = Pb + SZ_P;            // bf16 Qh (sorted)
    float* rinv = Qb + SZ_P;          // unused slot (layout stability)
    float* sqv = rinv + BN;
    float* cen = sqv + BN;            // unused (centroid in LDS), layout kept
    float* Pc = cen + SZ_CEN;
    float* Qc = Pc + SZ_PC;
    float* hcv = Qc + SZ_PC;
    int* order = (int*)(hcv + SZ_PC);
    int* mapping = order + BN;
    int* lsv = mapping + BN;
    int* nbrv = lsv + BN;
    int* cntk = nbrv + BN * KNB;
    int* offk = cntk + NB * NK;
    unsigned short* xpe = (unsigned short*)xpeRegion;
    float* Dbuf = Pb;  // spans Pb..Qb, dead before the P/Q gemm
    unsigned short* PmQh = (unsigned short*)Pb;
    unsigned short* Qh = (unsigned short*)Qb;
    unsigned short* out_t = (unsigned short*)xs;  // xs fp32 dead after cenpq
    unsigned short* frag = (unsigned short*)(offk + NB * NK);
    unsigned short* hn_frag = frag;               // slot 0: hn fragments (hv -> fc2)
    unsigned short* xs_frag = frag + SZ_XS;
    unsigned short* wf1 = frag + 2 * SZ_XS;
    unsigned short* wfpmq = wf1 + (size_t)NC * NC;    // (Wtop-Wbot) 192x384
    unsigned short* wfq = wfpmq + (size_t)NC * NCOUT; // Wbot 192x384
    unsigned short* wf2 = wfq + (size_t)NC * NCOUT;
    _Float16* xef = (_Float16*)(wf2 + (size_t)NCOUT * NC);

    // fused: conv | order | wcvt (independent; order's latency hides under conv)
    front_kernel<<<FRONT_CONV_BLOCKS + FRONT_ORDER_BLOCKS + FRONT_WCVT_BLOCKS, 256, 0, stream>>>(
        x, cpe_w, cpe_b, xpe, labels, order, mapping, lsv, cntk, offk, fc1_w, nn_v_w, fc2_w,
        wf1, wfpmq, wfq, wf2);
    // fc1 fused with transpose: reads xpe directly, writes xs fp32 (sorted) + xs_frag bf16
    fc1_kernel<<<NB * (NN / 64), 256, 0, stream>>>(xpe, wf1, fc1_b, xs, xs_frag, mapping);
    // xe fragments + rinv/sqv fused
    xe_cvt_kernel<<<dim3(LPMAX / 16, NK, NB), 384, 0, stream>>>(xs, offk, cntk, xef, sqv);
    gram_kernel<<<dim3(LPMAX / 64, LPMAX / 64, NB * NK), 256, 0, stream>>>(xef, sqv, offk,
                                                                           cntk, Dbuf);
    select9_kernel<<<dim3(NN / 4, NB), 256, 0, stream>>>(Dbuf, lsv, offk, cntk, nbrv);
    // merged P/Q GEMM, 2 col-halves: A read 2x instead of 6x
    gemm_mfma_pq2<<<NB * 2 * (NN / 64), 256, 0, stream>>>(xs_frag, wfpmq, wfq, nn_v_b, PmQh,
                                                          Qh);
    // merged centroids + cluster P/Q (centroid kept in LDS)
    cenpq_kernel<<<NB * NK, 768, 0, stream>>>(xs, offk, cntk, nn_c_w, nn_c_b, Pc, Qc);
    hcmax_kernel<<<NB * NK, NCOUT, 0, stream>>>(Pc, Qc, hcv);
    // hv: wide-grid gather (RESTORED — R3 lesson: keep gather TLP)
    hv_kernel<<<dim3(NN / 4, NB), 192, 0, stream>>>(PmQh, Qh, nbrv, lsv, hcv, hn_frag);
    // fc2: contiguous sorted rows (permutation lives in out_kernel's gather)
    gemm_mfma_hb<12><<<dim3(NC / 64, NN / 64, NB), 256, 0, stream>>>(
        hn_frag, SZ_P / NB, wf2, fc2_b, out_t, (size_t)NN * NC, NC);
    out_kernel<<<dim3(NC / 32, NN / 32, NB), dim3(32, 8), 0, stream>>>(out_t, x, mapping, out);
}

// Round 6
// 278.902 us; speedup vs baseline: 1.1896x; 1.1896x over previous
//
#include <hip/hip_runtime.h>
#include <math.h>

#define NB 8
#define NC 192
#define NH 56
#define NW 56
#define NN 3136      // NH*NW
#define NK 16        // clusters
#define KNB 9        // neighbors
#define NCOUT 384    // 2*NC
#define LPMAX 320    // max padded cluster size (L~196±14, 320 is >8 sigma)
#define DSTRIDE 320
#define DSLOT (320 * 320)

#define FLT_INF __builtin_inff()

typedef short s16x8 __attribute__((ext_vector_type(8)));
typedef _Float16 f16x8 __attribute__((ext_vector_type(8)));
typedef float f32x4 __attribute__((ext_vector_type(4)));
typedef unsigned short us8 __attribute__((ext_vector_type(8)));
typedef unsigned short us4 __attribute__((ext_vector_type(4)));

// gelu(tanh approx) via exact sigmoid identity: 0.5*(1+tanh(u)) = 1/(1+exp(-2u)).
__device__ __forceinline__ float gelu_t(float x) {
    const float k0 = 0.7978845608028654f;
    float u = k0 * (x + 0.044715f * x * x * x);
    float sg = __builtin_amdgcn_rcpf(1.0f + __expf(-2.0f * u));
    return x * sg;
}

__device__ __forceinline__ unsigned short f2bf(float f) {
    unsigned u = __float_as_uint(f);
    u += 0x7fff + ((u >> 16) & 1);  // round-to-nearest-even
    return (unsigned short)(u >> 16);
}

__device__ __forceinline__ float bf2f(unsigned short h) {
    return __uint_as_float(((unsigned)h) << 16);
}

// ============================================================================
// XCD batch-affinity (T1, batch-per-XCD): lin%8 = batch pins batch b's whole
// pipeline to XCD b; producer->consumer intermediates stay in its 4MiB L2.
// LESSON (R3): never fuse latency-bound gathers into compute-tile-shaped
// kernels — it destroys the TLP hiding the gather (fc2hv: 71µs @ 15% occ).
// LESSON (R4): never grow accumulator count past ~48 VGPRs in these streaming
// fragment-GEMMs — 96 acc regs killed occupancy+load-hoisting (pq2: 85µs @
// MfmaUtil 3%). A-re-reads are L2-resident (~3µs) — not worth registers.
// ============================================================================

// ---------------- fused front kernel: conv (blocks 0..1535) | order | wcvt
#define FRONT_CONV_BLOCKS (NB * NC)            // 1536
#define FRONT_ORDER_BLOCKS (NB * NK)           // 128
#define FRONT_WCVT_BLOCKS 288                  // 6*12*4
__global__ __launch_bounds__(256) void front_kernel(
    const float* __restrict__ X, const float* __restrict__ W7, const float* __restrict__ bias,
    unsigned short* __restrict__ xpe,
    const int* __restrict__ labels, int* __restrict__ order, int* __restrict__ mapping,
    int* __restrict__ lsv, int* __restrict__ cntk, int* __restrict__ offk,
    const float* __restrict__ Wf1, const float* __restrict__ Wv, const float* __restrict__ Wf2,
    unsigned short* __restrict__ wf1, unsigned short* __restrict__ wfpmq,
    unsigned short* __restrict__ wfq, unsigned short* __restrict__ wf2) {
    __shared__ float tile[62 * 62];
    __shared__ float wl[49];
    int bid = blockIdx.x;
    int tid = threadIdx.x;
    if (bid < FRONT_CONV_BLOCKS) {
        // -------- depthwise 7x7 conv + bias + residual -> bf16 xpe --------
        int bc = (bid & 7) * NC + (bid >> 3);  // XCD remap: batch = bid%8
        int c = bc % NC;
        const float* Xp = X + (size_t)bc * NN;
        if (tid < 49) wl[tid] = W7[(size_t)c * 49 + tid];
        for (int idx = tid; idx < 62 * 62; idx += 256) {
            int ty = idx / 62, tx = idx % 62;
            int gy = ty - 3, gx = tx - 3;
            float v = 0.0f;
            if (gy >= 0 && gy < NH && gx >= 0 && gx < NW) v = Xp[gy * NW + gx];
            tile[idx] = v;
        }
        __syncthreads();
        float cb = bias[c];
        for (int g = tid; g < (NN / 4); g += 256) {
            int y = g / (NW / 4), x0 = (g % (NW / 4)) * 4;
            float a0 = 0.f, a1 = 0.f, a2 = 0.f, a3 = 0.f;
#pragma unroll
            for (int dy = 0; dy < 7; ++dy) {
                const float* tr = &tile[(y + dy) * 62 + x0];
#pragma unroll
                for (int dx = 0; dx < 7; ++dx) {
                    float wv = wl[dy * 7 + dx];
                    a0 += tr[dx] * wv;
                    a1 += tr[dx + 1] * wv;
                    a2 += tr[dx + 2] * wv;
                    a3 += tr[dx + 3] * wv;
                }
            }
            const float* rr = &tile[(y + 3) * 62 + x0 + 3];
            us4 o;
            o[0] = f2bf(a0 + cb + rr[0]);
            o[1] = f2bf(a1 + cb + rr[1]);
            o[2] = f2bf(a2 + cb + rr[2]);
            o[3] = f2bf(a3 + cb + rr[3]);
            *(us4*)(xpe + (size_t)bc * NN + y * NW + x0) = o;
        }
    } else if (bid < FRONT_CONV_BLOCKS + FRONT_ORDER_BLOCKS) {
        // -------- stable counting sort (wave 0 only) --------
        if (tid >= 64) return;
        int idx = bid - FRONT_CONV_BLOCKS;
        int b = idx >> 4;
        int k = idx & 15;
        int lane = tid;
        const int* lb = labels + (size_t)b * NN;
        int cntLess = 0, cntEq = 0;
        for (int n0 = 0; n0 < NN; n0 += 64) {
            int lab = lb[n0 + lane] & 15;
            cntLess += __popcll(__ballot(lab < k));
            cntEq += __popcll(__ballot(lab == k));
        }
        int base = cntLess;
        int run = 0;
        for (int n0 = 0; n0 < NN; n0 += 64) {
            int n = n0 + lane;
            int lab = lb[n] & 15;
            bool p = (lab == k);
            unsigned long long mask = __ballot(p);
            int rank = __popcll(mask & ((1ull << lane) - 1ull));
            if (p) {
                int pos = base + run + rank;
                order[b * NN + pos] = n;
                mapping[b * NN + n] = pos;
                lsv[b * NN + pos] = k;
            }
            run += __popcll(mask);
        }
        if (lane == 0) {
            offk[b * NK + k] = base;
            cntk[b * NK + k] = cntEq;
        }
    } else {
        // -------- weight -> B-fragment conversions --------
        int u = bid - (FRONT_CONV_BLOCKS + FRONT_ORDER_BLOCKS);
        int nt = u % 6, kc = (u / 6) % 12, z = u / 72;
        const float* W;
        unsigned short* Bf;
        int ldw, rowoff, KC, NT;
        bool diff = false;
        if (z == 0) { W = Wf1; Bf = wf1; ldw = NC; rowoff = 0; KC = 6; NT = 3; }
        else if (z == 1) { W = Wv; Bf = wfpmq; ldw = NCOUT; rowoff = 0; KC = 6; NT = 6; diff = true; }
        else if (z == 2) { W = Wv; Bf = wfq; ldw = NCOUT; rowoff = NC; KC = 6; NT = 6; }
        else { W = Wf2; Bf = wf2; ldw = NC; rowoff = 0; KC = 12; NT = 3; }
        if (nt >= NT || kc >= KC) return;
        int c = tid >> 6, l = tid & 63;
        int n = l & 15, q = l >> 4;
        int col = nt * 64 + c * 16 + n;
        int krow = rowoff + kc * 32 + q * 8;
        unsigned short pack[8];
#pragma unroll
        for (int j = 0; j < 8; ++j) {
            float v = W[(size_t)(krow + j) * ldw + col];
            if (diff) v -= W[(size_t)(NC + krow + j) * ldw + col];
            pack[j] = f2bf(v);
        }
        *(us8*)(Bf + ((((size_t)nt * KC + kc) * 4 + c) * 64 + l) * 8) = *(const us8*)pack;
    }
}

// ---------------- fc1 fused with transpose: A-fragments built directly from xpe ----------------
// One block per (b, 64-row strip) x ALL 192 cols; A read exactly once. acc[12]=48 regs
// is the verified ceiling for this pattern (R4 lesson: 96 regs => latency collapse).
__global__ __launch_bounds__(256) void fc1_kernel(const unsigned short* __restrict__ xpe,
                                                  const unsigned short* __restrict__ Bf,
                                                  const float* __restrict__ bias,
                                                  float* __restrict__ xs,
                                                  unsigned short* __restrict__ Cfrag,
                                                  const int* __restrict__ rowmap) {
    int lin = blockIdx.x;              // 392 = 49*8
    int b = lin & 7, by = lin >> 3;    // XCD remap: batch = lin%8
    int w = threadIdx.x >> 6, lane = threadIdx.x & 63;
    int sg = by * 4 + w;
    int m = lane & 15, q = lane >> 4;
    int n = by * 64 + w * 16 + m;      // spatial row this lane's A-frag covers
    const unsigned short* Xb = xpe + (size_t)b * NC * NN + n;
    f32x4 acc[12] = {};
#pragma unroll
    for (int kc = 0; kc < 6; ++kc) {
        int ch = kc * 32 + q * 8;
        s16x8 a;
#pragma unroll
        for (int j = 0; j < 8; ++j) a[j] = (short)Xb[(size_t)(ch + j) * NN];
#pragma unroll
        for (int ct = 0; ct < 12; ++ct) {
            s16x8 bv = *(const s16x8*)(Bf + ((((size_t)(ct >> 2) * 6 + kc) * 4 + (ct & 3)) * 64 + lane) * 8);
            acc[ct] = __builtin_amdgcn_mfma_f32_16x16x32_bf16(a, bv, acc[ct], 0, 0, 0);
        }
    }
    float* Cb = xs + (size_t)b * NN * NC;
#pragma unroll
    for (int r = 0; r < 4; ++r) {
        int grow = sg * 16 + q * 4 + r;
        int orow = rowmap[(size_t)b * NN + grow];
        int s2 = orow >> 4, m2 = orow & 15;
#pragma unroll
        for (int ct = 0; ct < 12; ++ct) {
            int col = ct * 16 + m;
            float v = acc[ct][r] + bias[col];
            Cb[(size_t)orow * NC + col] = v;
            int kc2 = col >> 5, q2 = (col >> 3) & 3, j2 = col & 7;
            Cfrag[(size_t)b * NN * NC + (((size_t)s2 * 6 + kc2) * 64 + q2 * 16 + m2) * 8 + j2] =
                f2bf(v);
        }
    }
}

// ---------------- merged P/Q GEMM (R2-proven): acc 8x f32x4, 2352 blocks ----------------
template <int KC>
__global__ __launch_bounds__(256) void gemm_mfma_pq(const unsigned short* __restrict__ Af,
                                                    size_t aStride,
                                                    const unsigned short* __restrict__ B1,
                                                    const unsigned short* __restrict__ B2,
                                                    const float* __restrict__ bias,
                                                    unsigned short* __restrict__ PmQ,
                                                    unsigned short* __restrict__ Qh,
                                                    size_t cStride, int ldc) {
    // grid (6,49,8); XCD remap
    int lin = ((int)blockIdx.z * 49 + blockIdx.y) * 6 + blockIdx.x;
    int b = lin & 7, pos = lin >> 3;
    int bx = pos % 6, by = pos / 6;
    int w = threadIdx.x >> 6, lane = threadIdx.x & 63;
    int sg = by * 4 + w;
    int n0 = bx * 64;
    const unsigned short* Ap = Af + (size_t)b * aStride + ((size_t)sg * KC * 64 + lane) * 8;
    const unsigned short* Bp1 = B1 + ((size_t)bx * KC * 256 + lane) * 8;
    const unsigned short* Bp2 = B2 + ((size_t)bx * KC * 256 + lane) * 8;
    f32x4 acc1[4] = {};
    f32x4 acc2[4] = {};
#pragma unroll
    for (int kc = 0; kc < KC; ++kc) {
        s16x8 a = *(const s16x8*)(Ap + kc * 512);
#pragma unroll
        for (int c = 0; c < 4; ++c) {
            s16x8 b1 = *(const s16x8*)(Bp1 + kc * 2048 + c * 512);
            acc1[c] = __builtin_amdgcn_mfma_f32_16x16x32_bf16(a, b1, acc1[c], 0, 0, 0);
            s16x8 b2 = *(const s16x8*)(Bp2 + kc * 2048 + c * 512);
            acc2[c] = __builtin_amdgcn_mfma_f32_16x16x32_bf16(a, b2, acc2[c], 0, 0, 0);
        }
    }
    int col0 = lane & 15, rq = lane >> 4;
    unsigned short* Pb = PmQ + (size_t)b * cStride;
    unsigned short* Qb = Qh + (size_t)b * cStride;
#pragma unroll
    for (int r = 0; r < 4; ++r) {
        int grow = sg * 16 + rq * 4 + r;
#pragma unroll
        for (int c = 0; c < 4; ++c) {
            int col = n0 + c * 16 + col0;
            Pb[(size_t)grow * ldc + col] = f2bf(acc1[c][r] + bias[col]);
            Qb[(size_t)grow * ldc + col] = f2bf(acc2[c][r]);
        }
    }
}

// ---------------- xe = xs*rinv -> fp16 A-fragments; computes rinv + sqv in-kernel ----------------
__global__ __launch_bounds__(384) void xe_cvt_kernel(const float* __restrict__ xs,
                                                     const int* __restrict__ offk,
                                                     const int* __restrict__ cntk,
                                                     _Float16* __restrict__ xef,
                                                     float* __restrict__ sqv) {
    __shared__ float psum[16][25];
    __shared__ float rloc[16];
    // grid (20,16,8); XCD remap
    int lin = ((int)blockIdx.z * 16 + blockIdx.y) * 20 + blockIdx.x;
    int b = lin & 7, pos = lin >> 3;
    int k = pos / 20, strip = pos % 20;
    int bk = b * NK + k;
    int base = offk[bk], L = cntk[bk];
    if (strip * 16 >= L) return;
    int kc = threadIdx.x >> 6, l = threadIdx.x & 63;
    int m = l & 15, q = l >> 4;
    int rl = strip * 16 + m;
    int row = base + (rl < L ? rl : L - 1);
    const float* src = xs + ((size_t)b * NN + row) * NC + kc * 32 + q * 8;
    float4 v0 = *(const float4*)src;
    float4 v1 = *(const float4*)(src + 4);
    float part = v0.x * v0.x + v0.y * v0.y + v0.z * v0.z + v0.w * v0.w + v1.x * v1.x +
                 v1.y * v1.y + v1.z * v1.z + v1.w * v1.w;
    psum[m][kc * 4 + q] = part;
    __syncthreads();
    if (threadIdx.x < 16) {
        float s = 0.0f;
#pragma unroll
        for (int i2 = 0; i2 < 24; ++i2) s += psum[threadIdx.x][i2];
        float nrm = fmaxf(sqrtf(s), 1e-12f);
        float ri = 1.0f / nrm;
        rloc[threadIdx.x] = ri;
        if (strip * 16 + (int)threadIdx.x < L)
            sqv[(size_t)b * NN + base + strip * 16 + threadIdx.x] = (s * ri) * ri;
    }
    __syncthreads();
    float rv = rloc[m];
    f16x8 pack;
    pack[0] = (_Float16)(v0.x * rv);
    pack[1] = (_Float16)(v0.y * rv);
    pack[2] = (_Float16)(v0.z * rv);
    pack[3] = (_Float16)(v0.w * rv);
    pack[4] = (_Float16)(v1.x * rv);
    pack[5] = (_Float16)(v1.y * rv);
    pack[6] = (_Float16)(v1.z * rv);
    pack[7] = (_Float16)(v1.w * rv);
    *(f16x8*)(xef + (size_t)bk * (20 * 6 * 512) + (((size_t)strip * 6 + kc) * 64 + l) * 8) =
        pack;
}

// ---------------- Gram -> d2 tiles via fp16 MFMA (stores only live rows/cols) ----------------
__global__ __launch_bounds__(256) void gram_kernel(const _Float16* __restrict__ xef,
                                                   const float* __restrict__ sqv,
                                                   const int* __restrict__ offk,
                                                   const int* __restrict__ cntk,
                                                   float* __restrict__ D) {
    // grid (5,5,128); XCD remap
    int lin = ((int)blockIdx.z * 5 + blockIdx.y) * 5 + blockIdx.x;
    int b = lin & 7, pos = lin >> 3;
    int k = pos / 25, rr = pos % 25;
    int tj = rr / 5, ti = rr % 5;
    int bk = b * NK + k;
    int base = offk[bk], L = cntk[bk];
    if (ti * 64 >= L || tj * 64 >= L) return;
    int w = threadIdx.x >> 6, lane = threadIdx.x & 63;
    const _Float16* Xf = xef + (size_t)bk * (20 * 6 * 512);
    const _Float16* Ap = Xf + (((size_t)(ti * 4 + w) * 6) * 64 + lane) * 8;
    f32x4 acc[4] = {};
#pragma unroll
    for (int kc = 0; kc < 6; ++kc) {
        f16x8 a = *(const f16x8*)(Ap + kc * 512);
#pragma unroll
        for (int js = 0; js < 4; ++js) {
            f16x8 bv = *(const f16x8*)(Xf + (((size_t)(tj * 4 + js) * 6 + kc) * 64 + lane) * 8);
            acc[js] = __builtin_amdgcn_mfma_f32_16x16x32_f16(a, bv, acc[js], 0, 0, 0);
        }
    }
    float* Dr = D + (size_t)bk * DSLOT;
    const float* Sb = sqv + (size_t)b * NN + base;
    int col0 = lane & 15, rq = lane >> 4;
#pragma unroll
    for (int r = 0; r < 4; ++r) {
        int i = ti * 64 + w * 16 + rq * 4 + r;
        if (i >= L) continue;
        float si = Sb[i];
#pragma unroll
        for (int js = 0; js < 4; ++js) {
            int j = tj * 64 + js * 16 + col0;
            if (j < L) Dr[(size_t)i * DSTRIDE + j] = si + Sb[j] - 2.0f * acc[js][r];
        }
    }
}

// ---------------- top-9 selection: one wave per row (sorted ids) ----------------
#define LEXLT(da, ca, db, cb) ((da) < (db) || ((da) == (db) && (ca) < (cb)))
__global__ __launch_bounds__(256) void select9_kernel(const float* __restrict__ D,
                                                      const int* __restrict__ lsv,
                                                      const int* __restrict__ offk,
                                                      const int* __restrict__ cntk,
                                                      int* __restrict__ nbr) {
    // grid (784,8); XCD remap
    int lin = (int)blockIdx.y * 784 + blockIdx.x;
    int b = lin & 7, quad = lin >> 3;
    int r = quad * 4 + (threadIdx.x >> 6);
    int lane = threadIdx.x & 63;
    int k = lsv[(size_t)b * NN + r];
    int bk = b * NK + k;
    int base = offk[bk], L = cntk[bk];
    int Lc = L < LPMAX ? L : LPMAX;
    const float* Dr = D + (size_t)bk * DSLOT + (size_t)(r - base) * DSTRIDE;
    float d0, d1, d2, d3, d4;
    int c0, c1, c2, c3, c4;
    c0 = lane;
    c1 = lane + 64;
    c2 = lane + 128;
    c3 = lane + 192;
    c4 = lane + 256;
    d0 = c0 < Lc ? Dr[c0] : FLT_INF;
    d1 = c1 < Lc ? Dr[c1] : FLT_INF;
    d2 = c2 < Lc ? Dr[c2] : FLT_INF;
    d3 = c3 < Lc ? Dr[c3] : FLT_INF;
    d4 = c4 < Lc ? Dr[c4] : FLT_INF;
#define CS(da, ca, db, cb)                  \
    if (LEXLT(db, cb, da, ca)) {            \
        float t = da; da = db; db = t;      \
        int u = ca; ca = cb; cb = u;        \
    }
    CS(d0, c0, d1, c1) CS(d3, c3, d4, c4) CS(d2, c2, d4, c4) CS(d2, c2, d3, c3)
    CS(d1, c1, d4, c4) CS(d0, c0, d3, c3) CS(d0, c0, d2, c2) CS(d1, c1, d3, c3)
    CS(d1, c1, d2, c2)
#undef CS
    size_t row = (size_t)b * NN + r;
    for (int q = 0; q < KNB; ++q) {
        float bd = d0;
        int bc = c0;
#pragma unroll
        for (int m = 32; m; m >>= 1) {
            float od = __shfl_xor(bd, m, 64);
            int oc = __shfl_xor(bc, m, 64);
            if (LEXLT(od, oc, bd, bc)) {
                bd = od;
                bc = oc;
            }
        }
        if (lane == 0) nbr[row * KNB + q] = base + bc;
        if (d0 == bd && c0 == bc) {
            d0 = d1; c0 = c1;
            d1 = d2; c1 = c2;
            d2 = d3; c2 = c3;
            d3 = d4; c3 = c4;
            d4 = FLT_INF; c4 = 0x7fffffff;
        }
    }
}

// ---------------- merged centroids + cluster P/Q (one block per bk) ----------------
__global__ __launch_bounds__(768) void cenpq_kernel(const float* __restrict__ xs,
                                                    const int* __restrict__ offk,
                                                    const int* __restrict__ cntk,
                                                    const float* __restrict__ Wc,
                                                    const float* __restrict__ bc,
                                                    float* __restrict__ Pc,
                                                    float* __restrict__ Qc) {
    __shared__ float part[4][NC];
    __shared__ float ce[NC];
    __shared__ float pcs[NCOUT], qcs[NCOUT];
    // XCD remap: bk = (bid%8)*16 + bid/8
    int bk = ((int)blockIdx.x & 7) * NK + ((int)blockIdx.x >> 3);
    int b = bk >> 4;
    int base = offk[bk], L = cntk[bk];
    int w = threadIdx.x / NC;  // 0..3 row partition
    int c = threadIdx.x % NC;
    const float* Xb = xs + ((size_t)b * NN + base) * NC + c;
    float s = 0.0f;
    for (int r = w; r < L; r += 4) s += Xb[(size_t)r * NC];
    part[w][c] = s;
    __syncthreads();
    if (threadIdx.x < NC) {
        int cc = threadIdx.x;
        float tot = part[0][cc] + part[1][cc] + part[2][cc] + part[3][cc];
        ce[cc] = tot / fmaxf((float)L, 1.0f);
    }
    __syncthreads();
    int o = threadIdx.x % NCOUT, half = threadIdx.x / NCOUT;
    float pc = 0.0f, qc = 0.0f;
    int cs = half * 96, cend = cs + 96;
    for (int c2 = cs; c2 < cend; ++c2) {
        float cv = ce[c2];
        pc += cv * Wc[(size_t)c2 * NCOUT + o];
        qc += cv * Wc[(size_t)(NC + c2) * NCOUT + o];
    }
    if (half == 1) {
        pcs[o] = pc;
        qcs[o] = qc;
    }
    __syncthreads();
    if (half == 0) {
        Pc[(size_t)bk * NCOUT + o] = pc + pcs[o] + bc[o];
        Qc[(size_t)bk * NCOUT + o] = qc + qcs[o];
    }
}

// ---------------- cluster message max (valley trick, 128 blocks) ----------------
__global__ __launch_bounds__(384) void hcmax_kernel(const float* __restrict__ Pc,
                                                    const float* __restrict__ Qc,
                                                    float* __restrict__ hc) {
    int bk = ((int)blockIdx.x & 7) * NK + ((int)blockIdx.x >> 3);
    int b = bk >> 4, i = bk & 15;
    int o = threadIdx.x;
    float pi = Pc[((size_t)b * NK + i) * NCOUT + o];
    float qi = Qc[((size_t)b * NK + i) * NCOUT + o];
    float pmq = pi - qi;
    float qmn = FLT_INF, qmx = -FLT_INF;
    for (int j = 0; j < NK; ++j) {
        float v = Qc[((size_t)b * NK + j) * NCOUT + o];
        qmn = fminf(qmn, v);
        qmx = fmaxf(qmx, v);
    }
    hc[((size_t)b * NK + i) * NCOUT + o] =
        fmaxf(gelu_t(pmq + qmn), gelu_t(pmq + qmx));
}

// ---------------- node max + cluster term -> hn bf16 A-fragments (wide-grid gather) ----------------
__global__ __launch_bounds__(192) void hv_kernel(const unsigned short* __restrict__ PmQ,
                                                 const unsigned short* __restrict__ Qh,
                                                 const int* __restrict__ nbr,
                                                 const int* __restrict__ lsv,
                                                 const float* __restrict__ hc,
                                                 unsigned short* __restrict__ hnf) {
    // grid (784,8); XCD remap: b = lin%8 -> gather into Qh[b] is L2-local
    int lin = (int)blockIdx.y * 784 + blockIdx.x;
    int b = lin & 7, quad = lin >> 3;
    int t = threadIdx.x;           // 192 = 4 rows x 48 channel-chunks
    int rsub = t / 48, c = t % 48;
    int i = quad * 4 + rsub;
    size_t row = (size_t)b * NN + i;
    int lab = lsv[row];
    int o0 = c * 8;
    int jn[KNB];
#pragma unroll
    for (int q = 0; q < KNB; ++q) jn[q] = nbr[row * KNB + q];
    const unsigned short* Qbb = Qh + (size_t)b * NN * NCOUT + o0;
    us8 pv = *(const us8*)(PmQ + row * NCOUT + o0);
    us8 q0 = *(const us8*)(Qbb + (size_t)jn[0] * NCOUT);
    float qmn[8], qmx[8];
#pragma unroll
    for (int e = 0; e < 8; ++e) {
        float v = bf2f(q0[e]);
        qmn[e] = v;
        qmx[e] = v;
    }
#pragma unroll
    for (int q = 1; q < KNB; ++q) {
        us8 qv = *(const us8*)(Qbb + (size_t)jn[q] * NCOUT);
#pragma unroll
        for (int e = 0; e < 8; ++e) {
            float v = bf2f(qv[e]);
            qmn[e] = fminf(qmn[e], v);
            qmx[e] = fmaxf(qmx[e], v);
        }
    }
    const float* hcr = hc + ((size_t)b * NK + lab) * NCOUT + o0;
    float4 h0 = *(const float4*)hcr;
    float4 h1 = *(const float4*)(hcr + 4);
    float hcv[8] = {h0.x, h0.y, h0.z, h0.w, h1.x, h1.y, h1.z, h1.w};
    unsigned short pack[8];
#pragma unroll
    for (int e = 0; e < 8; ++e) {
        float pmq = bf2f(pv[e]);
        float m = fmaxf(gelu_t(pmq + qmn[e]), gelu_t(pmq + qmx[e]));
        pack[e] = f2bf(m + hcv[e]);
    }
    int s = i >> 4, mm = i & 15;
    *(us8*)(hnf + (size_t)b * NN * NCOUT +
            (((size_t)s * 12 + (c >> 2)) * 64 + (c & 3) * 16 + mm) * 8) = *(const us8*)pack;
}

// ---------------- fc2: bf16 out + bias, contiguous sorted rows ----------------
template <int KC>
__global__ __launch_bounds__(256) void gemm_mfma_hb(const unsigned short* __restrict__ Af,
                                                    size_t aStride,
                                                    const unsigned short* __restrict__ Bf,
                                                    const float* __restrict__ bias,
                                                    unsigned short* __restrict__ C,
                                                    size_t cStride, int ldc) {
    // grid (3,49,8); XCD remap
    int lin = ((int)blockIdx.z * 49 + blockIdx.y) * 3 + blockIdx.x;
    int b = lin & 7, pos = lin >> 3;
    int bx = pos % 3, by = pos / 3;
    int w = threadIdx.x >> 6, lane = threadIdx.x & 63;
    int sg = by * 4 + w;
    int n0 = bx * 64;
    const unsigned short* Ap = Af + (size_t)b * aStride + ((size_t)sg * KC * 64 + lane) * 8;
    const unsigned short* Bp = Bf + ((size_t)bx * KC * 256 + lane) * 8;
    f32x4 acc[4] = {};
#pragma unroll
    for (int kc = 0; kc < KC; ++kc) {
        s16x8 a = *(const s16x8*)(Ap + kc * 512);
#pragma unroll
        for (int c = 0; c < 4; ++c) {
            s16x8 bv = *(const s16x8*)(Bp + kc * 2048 + c * 512);
            acc[c] = __builtin_amdgcn_mfma_f32_16x16x32_bf16(a, bv, acc[c], 0, 0, 0);
        }
    }
    int col0 = lane & 15, rq = lane >> 4;
    unsigned short* Cb = C + (size_t)b * cStride;
#pragma unroll
    for (int r = 0; r < 4; ++r) {
        int grow = sg * 16 + rq * 4 + r;
#pragma unroll
        for (int c = 0; c < 4; ++c) {
            int col = n0 + c * 16 + col0;
            Cb[(size_t)grow * ldc + col] = f2bf(acc[c][r] + bias[col]);
        }
    }
}

// ---------------- transpose (b,n,c)->(b,c,n) + residual; row gather via mapping ----------------
__global__ void out_kernel(const unsigned short* __restrict__ T, const float* __restrict__ X,
                           const int* __restrict__ mapping, float* __restrict__ Y) {
    __shared__ float t[32][33];
    // grid (6,98,8); XCD remap
    int lin = ((int)blockIdx.z * 98 + blockIdx.y) * 6 + blockIdx.x;
    int b = lin & 7, pos = lin >> 3;
    int c0 = (pos % 6) * 32, n0 = (pos / 6) * 32;
    int tx = threadIdx.x, ty = threadIdx.y;  // 32 x 8
#pragma unroll
    for (int q = 0; q < 4; ++q) {
        int n = n0 + ty + q * 8;
        int srow = mapping[(size_t)b * NN + n];
        t[ty + q * 8][tx] = bf2f(T[((size_t)b * NN + srow) * NC + c0 + tx]);
    }
    __syncthreads();
#pragma unroll
    for (int q = 0; q < 4; ++q) {
        int c = c0 + ty + q * 8;
        size_t idx = ((size_t)b * NC + c) * NN + n0 + tx;
        Y[idx] = t[tx][ty + q * 8] + X[idx];
    }
}

extern "C" void kernel_launch(void* const* d_in, const int* in_sizes, int n_in, void* d_out,
                              int out_size, void* d_ws, size_t ws_size, hipStream_t stream) {
    const float* x = (const float*)d_in[0];
    const int* labels = (const int*)d_in[1];
    const float* cpe_w = (const float*)d_in[2];
    const float* cpe_b = (const float*)d_in[3];
    const float* fc1_w = (const float*)d_in[4];
    const float* fc1_b = (const float*)d_in[5];
    const float* nn_v_w = (const float*)d_in[6];
    const float* nn_v_b = (const float*)d_in[7];
    const float* nn_c_w = (const float*)d_in[8];
    const float* nn_c_b = (const float*)d_in[9];
    const float* fc2_w = (const float*)d_in[10];
    const float* fc2_b = (const float*)d_in[11];
    float* out = (float*)d_out;

    const size_t SZ_XS = (size_t)NB * NN * NC;
    const size_t SZ_P = (size_t)NB * NN * NCOUT;
    const size_t BN = (size_t)NB * NN;
    const size_t SZ_CEN = (size_t)NB * NK * NC;
    const size_t SZ_PC = (size_t)NB * NK * NCOUT;

    float* base = (float*)d_ws;
    float* xs = base;                 // sorted fc1 out (fp32); reused as bf16 out_t later
    float* xpeRegion = xs + SZ_XS;    // bf16 conv out (ushort)
    float* Pb = xpeRegion + SZ_XS;    // bf16 PmQ (sorted); Dbuf during knn
    float* Qb = Pb + SZ_P;            // bf16 Qh (sorted)
    float* rinv = Qb + SZ_P;          // unused slot (layout stability)
    float* sqv = rinv + BN;
    float* cen = sqv + BN;            // unused (centroid in LDS), layout kept
    float* Pc = cen + SZ_CEN;
    float* Qc = Pc + SZ_PC;
    float* hcv = Qc + SZ_PC;
    int* order = (int*)(hcv + SZ_PC);
    int* mapping = order + BN;
    int* lsv = mapping + BN;
    int* nbrv = lsv + BN;
    int* cntk = nbrv + BN * KNB;
    int* offk = cntk + NB * NK;
    unsigned short* xpe = (unsigned short*)xpeRegion;
    float* Dbuf = Pb;  // spans Pb..Qb, dead before the P/Q gemm
    unsigned short* PmQh = (unsigned short*)Pb;
    unsigned short* Qh = (unsigned short*)Qb;
    unsigned short* out_t = (unsigned short*)xs;  // xs fp32 dead after cenpq
    unsigned short* frag = (unsigned short*)(offk + NB * NK);
    unsigned short* hn_frag = frag;               // slot 0: hn fragments (hv -> fc2)
    unsigned short* xs_frag = frag + SZ_XS;
    unsigned short* wf1 = frag + 2 * SZ_XS;
    unsigned short* wfpmq = wf1 + (size_t)NC * NC;    // (Wtop-Wbot) 192x384
    unsigned short* wfq = wfpmq + (size_t)NC * NCOUT; // Wbot 192x384
    unsigned short* wf2 = wfq + (size_t)NC * NCOUT;
    _Float16* xef = (_Float16*)(wf2 + (size_t)NCOUT * NC);

    // fused: conv | order | wcvt (independent; order's latency hides under conv)
    front_kernel<<<FRONT_CONV_BLOCKS + FRONT_ORDER_BLOCKS + FRONT_WCVT_BLOCKS, 256, 0, stream>>>(
        x, cpe_w, cpe_b, xpe, labels, order, mapping, lsv, cntk, offk, fc1_w, nn_v_w, fc2_w,
        wf1, wfpmq, wfq, wf2);
    // fc1 fused with transpose: reads xpe directly, writes xs fp32 (sorted) + xs_frag bf16
    fc1_kernel<<<NB * (NN / 64), 256, 0, stream>>>(xpe, wf1, fc1_b, xs, xs_frag, mapping);
    // xe fragments + rinv/sqv fused
    xe_cvt_kernel<<<dim3(LPMAX / 16, NK, NB), 384, 0, stream>>>(xs, offk, cntk, xef, sqv);
    gram_kernel<<<dim3(LPMAX / 64, LPMAX / 64, NB * NK), 256, 0, stream>>>(xef, sqv, offk,
                                                                           cntk, Dbuf);
    select9_kernel<<<dim3(NN / 4, NB), 256, 0, stream>>>(Dbuf, lsv, offk, cntk, nbrv);
    // merged P/Q GEMM (R2-proven shape: acc 8x f32x4, 2352 blocks)
    gemm_mfma_pq<6><<<dim3(NCOUT / 64, NN / 64, NB), 256, 0, stream>>>(
        xs_frag, SZ_XS / NB, wfpmq, wfq, nn_v_b, PmQh, Qh, (size_t)NN * NCOUT, NCOUT);
    // merged centroids + cluster P/Q (centroid kept in LDS)
    cenpq_kernel<<<NB * NK, 768, 0, stream>>>(xs, offk, cntk, nn_c_w, nn_c_b, Pc, Qc);
    hcmax_kernel<<<NB * NK, NCOUT, 0, stream>>>(Pc, Qc, hcv);
    // hv: wide-grid gather (R3 lesson: keep gather TLP)
    hv_kernel<<<dim3(NN / 4, NB), 192, 0, stream>>>(PmQh, Qh, nbrv, lsv, hcv, hn_frag);
    // fc2: contiguous sorted rows (permutation lives in out_kernel's gather)
    gemm_mfma_hb<12><<<dim3(NC / 64, NN / 64, NB), 256, 0, stream>>>(
        hn_frag, SZ_P / NB, wf2, fc2_b, out_t, (size_t)NN * NC, NC);
    out_kernel<<<dim3(NC / 32, NN / 32, NB), dim3(32, 8), 0, stream>>>(out_t, x, mapping, out);
}

// Round 7
// 267.412 us; speedup vs baseline: 1.2407x; 1.0430x over previous
//
#include <hip/hip_runtime.h>
#include <math.h>

#define NB 8
#define NC 192
#define NH 56
#define NW 56
#define NN 3136      // NH*NW
#define NK 16        // clusters
#define KNB 9        // neighbors
#define NCOUT 384    // 2*NC
#define LPMAX 320    // max padded cluster size (L~196±14, 320 is >8 sigma)
#define DSTRIDE 320
#define DSLOT (320 * 320)

#define FLT_INF __builtin_inff()

typedef short s16x8 __attribute__((ext_vector_type(8)));
typedef _Float16 f16x8 __attribute__((ext_vector_type(8)));
typedef float f32x4 __attribute__((ext_vector_type(4)));
typedef unsigned short us8 __attribute__((ext_vector_type(8)));
typedef unsigned short us4 __attribute__((ext_vector_type(4)));

// gelu(tanh approx) via exact sigmoid identity: 0.5*(1+tanh(u)) = 1/(1+exp(-2u)).
__device__ __forceinline__ float gelu_t(float x) {
    const float k0 = 0.7978845608028654f;
    float u = k0 * (x + 0.044715f * x * x * x);
    float sg = __builtin_amdgcn_rcpf(1.0f + __expf(-2.0f * u));
    return x * sg;
}

__device__ __forceinline__ unsigned short f2bf(float f) {
    unsigned u = __float_as_uint(f);
    u += 0x7fff + ((u >> 16) & 1);  // round-to-nearest-even
    return (unsigned short)(u >> 16);
}

__device__ __forceinline__ float bf2f(unsigned short h) {
    return __uint_as_float(((unsigned)h) << 16);
}

// ============================================================================
// XCD batch-affinity (T1, batch-per-XCD): lin%8 = batch pins batch b's whole
// pipeline to XCD b; producer->consumer intermediates stay in its 4MiB L2.
// LESSON (R3): never fuse latency-bound gathers into compute-tile-shaped
// kernels (fc2hv: 71µs @ 15% occ). LESSON (R4): never grow accumulators past
// ~48 VGPRs in streaming fragment-GEMMs (pq2: 85µs @ MfmaUtil 3%).
// LESSON (R6): ~70µs of the budget is SERIALIZATION, not kernel floors —
// this round horizontally fuses independent dispatches (the R1-proven
// pattern): 12 launches -> 8, enabled by un-aliasing D from Pb.
// All fused branches keep their exact bodies: bit-exact.
// ============================================================================

// ---------------- fused front kernel: conv (blocks 0..1535) | order | wcvt
#define FRONT_CONV_BLOCKS (NB * NC)            // 1536
#define FRONT_ORDER_BLOCKS (NB * NK)           // 128
#define FRONT_WCVT_BLOCKS 288                  // 6*12*4
__global__ __launch_bounds__(256) void front_kernel(
    const float* __restrict__ X, const float* __restrict__ W7, const float* __restrict__ bias,
    unsigned short* __restrict__ xpe,
    const int* __restrict__ labels, int* __restrict__ order, int* __restrict__ mapping,
    int* __restrict__ lsv, int* __restrict__ cntk, int* __restrict__ offk,
    const float* __restrict__ Wf1, const float* __restrict__ Wv, const float* __restrict__ Wf2,
    unsigned short* __restrict__ wf1, unsigned short* __restrict__ wfpmq,
    unsigned short* __restrict__ wfq, unsigned short* __restrict__ wf2) {
    __shared__ float tile[62 * 62];
    __shared__ float wl[49];
    int bid = blockIdx.x;
    int tid = threadIdx.x;
    if (bid < FRONT_CONV_BLOCKS) {
        int bc = (bid & 7) * NC + (bid >> 3);  // XCD remap: batch = bid%8
        int c = bc % NC;
        const float* Xp = X + (size_t)bc * NN;
        if (tid < 49) wl[tid] = W7[(size_t)c * 49 + tid];
        for (int idx = tid; idx < 62 * 62; idx += 256) {
            int ty = idx / 62, tx = idx % 62;
            int gy = ty - 3, gx = tx - 3;
            float v = 0.0f;
            if (gy >= 0 && gy < NH && gx >= 0 && gx < NW) v = Xp[gy * NW + gx];
            tile[idx] = v;
        }
        __syncthreads();
        float cb = bias[c];
        for (int g = tid; g < (NN / 4); g += 256) {
            int y = g / (NW / 4), x0 = (g % (NW / 4)) * 4;
            float a0 = 0.f, a1 = 0.f, a2 = 0.f, a3 = 0.f;
#pragma unroll
            for (int dy = 0; dy < 7; ++dy) {
                const float* tr = &tile[(y + dy) * 62 + x0];
#pragma unroll
                for (int dx = 0; dx < 7; ++dx) {
                    float wv = wl[dy * 7 + dx];
                    a0 += tr[dx] * wv;
                    a1 += tr[dx + 1] * wv;
                    a2 += tr[dx + 2] * wv;
                    a3 += tr[dx + 3] * wv;
                }
            }
            const float* rr = &tile[(y + 3) * 62 + x0 + 3];
            us4 o;
            o[0] = f2bf(a0 + cb + rr[0]);
            o[1] = f2bf(a1 + cb + rr[1]);
            o[2] = f2bf(a2 + cb + rr[2]);
            o[3] = f2bf(a3 + cb + rr[3]);
            *(us4*)(xpe + (size_t)bc * NN + y * NW + x0) = o;
        }
    } else if (bid < FRONT_CONV_BLOCKS + FRONT_ORDER_BLOCKS) {
        if (tid >= 64) return;
        int idx = bid - FRONT_CONV_BLOCKS;
        int b = idx >> 4;
        int k = idx & 15;
        int lane = tid;
        const int* lb = labels + (size_t)b * NN;
        int cntLess = 0, cntEq = 0;
        for (int n0 = 0; n0 < NN; n0 += 64) {
            int lab = lb[n0 + lane] & 15;
            cntLess += __popcll(__ballot(lab < k));
            cntEq += __popcll(__ballot(lab == k));
        }
        int base = cntLess;
        int run = 0;
        for (int n0 = 0; n0 < NN; n0 += 64) {
            int n = n0 + lane;
            int lab = lb[n] & 15;
            bool p = (lab == k);
            unsigned long long mask = __ballot(p);
            int rank = __popcll(mask & ((1ull << lane) - 1ull));
            if (p) {
                int pos = base + run + rank;
                order[b * NN + pos] = n;
                mapping[b * NN + n] = pos;
                lsv[b * NN + pos] = k;
            }
            run += __popcll(mask);
        }
        if (lane == 0) {
            offk[b * NK + k] = base;
            cntk[b * NK + k] = cntEq;
        }
    } else {
        int u = bid - (FRONT_CONV_BLOCKS + FRONT_ORDER_BLOCKS);
        int nt = u % 6, kc = (u / 6) % 12, z = u / 72;
        const float* W;
        unsigned short* Bf;
        int ldw, rowoff, KC, NT;
        bool diff = false;
        if (z == 0) { W = Wf1; Bf = wf1; ldw = NC; rowoff = 0; KC = 6; NT = 3; }
        else if (z == 1) { W = Wv; Bf = wfpmq; ldw = NCOUT; rowoff = 0; KC = 6; NT = 6; diff = true; }
        else if (z == 2) { W = Wv; Bf = wfq; ldw = NCOUT; rowoff = NC; KC = 6; NT = 6; }
        else { W = Wf2; Bf = wf2; ldw = NC; rowoff = 0; KC = 12; NT = 3; }
        if (nt >= NT || kc >= KC) return;
        int c = tid >> 6, l = tid & 63;
        int n = l & 15, q = l >> 4;
        int col = nt * 64 + c * 16 + n;
        int krow = rowoff + kc * 32 + q * 8;
        unsigned short pack[8];
#pragma unroll
        for (int j = 0; j < 8; ++j) {
            float v = W[(size_t)(krow + j) * ldw + col];
            if (diff) v -= W[(size_t)(NC + krow + j) * ldw + col];
            pack[j] = f2bf(v);
        }
        *(us8*)(Bf + ((((size_t)nt * KC + kc) * 4 + c) * 64 + l) * 8) = *(const us8*)pack;
    }
}

// ---------------- fc1 fused with transpose (verified win; acc[12]=48 regs ceiling) ----------------
__global__ __launch_bounds__(256) void fc1_kernel(const unsigned short* __restrict__ xpe,
                                                  const unsigned short* __restrict__ Bf,
                                                  const float* __restrict__ bias,
                                                  float* __restrict__ xs,
                                                  unsigned short* __restrict__ Cfrag,
                                                  const int* __restrict__ rowmap) {
    int lin = blockIdx.x;              // 392 = 49*8
    int b = lin & 7, by = lin >> 3;
    int w = threadIdx.x >> 6, lane = threadIdx.x & 63;
    int sg = by * 4 + w;
    int m = lane & 15, q = lane >> 4;
    int n = by * 64 + w * 16 + m;
    const unsigned short* Xb = xpe + (size_t)b * NC * NN + n;
    f32x4 acc[12] = {};
#pragma unroll
    for (int kc = 0; kc < 6; ++kc) {
        int ch = kc * 32 + q * 8;
        s16x8 a;
#pragma unroll
        for (int j = 0; j < 8; ++j) a[j] = (short)Xb[(size_t)(ch + j) * NN];
#pragma unroll
        for (int ct = 0; ct < 12; ++ct) {
            s16x8 bv = *(const s16x8*)(Bf + ((((size_t)(ct >> 2) * 6 + kc) * 4 + (ct & 3)) * 64 + lane) * 8);
            acc[ct] = __builtin_amdgcn_mfma_f32_16x16x32_bf16(a, bv, acc[ct], 0, 0, 0);
        }
    }
    float* Cb = xs + (size_t)b * NN * NC;
#pragma unroll
    for (int r = 0; r < 4; ++r) {
        int grow = sg * 16 + q * 4 + r;
        int orow = rowmap[(size_t)b * NN + grow];
        int s2 = orow >> 4, m2 = orow & 15;
#pragma unroll
        for (int ct = 0; ct < 12; ++ct) {
            int col = ct * 16 + m;
            float v = acc[ct][r] + bias[col];
            Cb[(size_t)orow * NC + col] = v;
            int kc2 = col >> 5, q2 = (col >> 3) & 3, j2 = col & 7;
            Cfrag[(size_t)b * NN * NC + (((size_t)s2 * 6 + kc2) * 64 + q2 * 16 + m2) * 8 + j2] =
                f2bf(v);
        }
    }
}

// ---------------- L3 fused: xe_cvt (blocks 0..2559) | cenpq (2560..2687), 384 threads ----------------
// cenpq rewritten for 384 threads BIT-EXACTLY: same part[4][NC] partials (each thread
// computes two row-partitions), same (half0+half1)+bias association in the P/Q dot.
#define MID_XE_BLOCKS 2560   // 20*16*8
#define MID_CEN_BLOCKS 128
__global__ __launch_bounds__(384) void mid_kernel(const float* __restrict__ xs,
                                                  const int* __restrict__ offk,
                                                  const int* __restrict__ cntk,
                                                  _Float16* __restrict__ xef,
                                                  float* __restrict__ sqv,
                                                  const float* __restrict__ Wc,
                                                  const float* __restrict__ bc,
                                                  float* __restrict__ Pc,
                                                  float* __restrict__ Qc) {
    __shared__ float psum[16][25];
    __shared__ float rloc[16];
    __shared__ float part[4][NC];
    __shared__ float ce[NC];
    int bid = blockIdx.x;
    if (bid < MID_XE_BLOCKS) {
        // -------- xe = xs*rinv -> fp16 A-fragments; rinv + sqv in-kernel --------
        int lin = bid;
        int b = lin & 7, pos = lin >> 3;
        int k = pos / 20, strip = pos % 20;
        int bk = b * NK + k;
        int base = offk[bk], L = cntk[bk];
        if (strip * 16 >= L) return;
        int kc = threadIdx.x >> 6, l = threadIdx.x & 63;
        int m = l & 15, q = l >> 4;
        int rl = strip * 16 + m;
        int row = base + (rl < L ? rl : L - 1);
        const float* src = xs + ((size_t)b * NN + row) * NC + kc * 32 + q * 8;
        float4 v0 = *(const float4*)src;
        float4 v1 = *(const float4*)(src + 4);
        float part2 = v0.x * v0.x + v0.y * v0.y + v0.z * v0.z + v0.w * v0.w + v1.x * v1.x +
                      v1.y * v1.y + v1.z * v1.z + v1.w * v1.w;
        psum[m][kc * 4 + q] = part2;
        __syncthreads();
        if (threadIdx.x < 16) {
            float s = 0.0f;
#pragma unroll
            for (int i2 = 0; i2 < 24; ++i2) s += psum[threadIdx.x][i2];
            float nrm = fmaxf(sqrtf(s), 1e-12f);
            float ri = 1.0f / nrm;
            rloc[threadIdx.x] = ri;
            if (strip * 16 + (int)threadIdx.x < L)
                sqv[(size_t)b * NN + base + strip * 16 + threadIdx.x] = (s * ri) * ri;
        }
        __syncthreads();
        float rv = rloc[m];
        f16x8 pack;
        pack[0] = (_Float16)(v0.x * rv);
        pack[1] = (_Float16)(v0.y * rv);
        pack[2] = (_Float16)(v0.z * rv);
        pack[3] = (_Float16)(v0.w * rv);
        pack[4] = (_Float16)(v1.x * rv);
        pack[5] = (_Float16)(v1.y * rv);
        pack[6] = (_Float16)(v1.z * rv);
        pack[7] = (_Float16)(v1.w * rv);
        *(f16x8*)(xef + (size_t)bk * (20 * 6 * 512) + (((size_t)strip * 6 + kc) * 64 + l) * 8) =
            pack;
    } else {
        // -------- centroids + cluster P/Q (bit-exact 384-thread form) --------
        int idx = bid - MID_XE_BLOCKS;
        int bk = ((idx & 7) * NK) + (idx >> 3);  // XCD remap
        int b = bk >> 4;
        int base = offk[bk], L = cntk[bk];
        int c = threadIdx.x % NC;
        int w2 = threadIdx.x / NC;  // 0..1; this thread covers partitions w2 and w2+2
        const float* Xb = xs + ((size_t)b * NN + base) * NC + c;
        float s0 = 0.0f, s1 = 0.0f;
        for (int r = w2; r < L; r += 4) s0 += Xb[(size_t)r * NC];
        for (int r = w2 + 2; r < L; r += 4) s1 += Xb[(size_t)r * NC];
        part[w2][c] = s0;
        part[w2 + 2][c] = s1;
        __syncthreads();
        if (threadIdx.x < NC) {
            int cc = threadIdx.x;
            float tot = part[0][cc] + part[1][cc] + part[2][cc] + part[3][cc];
            ce[cc] = tot / fmaxf((float)L, 1.0f);
        }
        __syncthreads();
        int o = threadIdx.x;  // 0..383
        float pcA = 0.0f, qcA = 0.0f, pcB = 0.0f, qcB = 0.0f;
        for (int c2 = 0; c2 < 96; ++c2) {
            float cv = ce[c2];
            pcA += cv * Wc[(size_t)c2 * NCOUT + o];
            qcA += cv * Wc[(size_t)(NC + c2) * NCOUT + o];
        }
        for (int c2 = 96; c2 < 192; ++c2) {
            float cv = ce[c2];
            pcB += cv * Wc[(size_t)c2 * NCOUT + o];
            qcB += cv * Wc[(size_t)(NC + c2) * NCOUT + o];
        }
        Pc[(size_t)bk * NCOUT + o] = pcA + pcB + bc[o];
        Qc[(size_t)bk * NCOUT + o] = qcA + qcB;
    }
}

// ---------------- L4 fused: pq GEMM (blocks 0..2351) | gram (2352..5551), 256 threads ----------------
// Independent once D is un-aliased from Pb: pq reads xs_frag/writes PmQ+Qh; gram reads
// xef/sqv, writes D. gram's ~10µs hides under pq. Both bodies unchanged: bit-exact.
#define L4_PQ_BLOCKS 2352    // 6*49*8
#define L4_GRAM_BLOCKS 3200  // 5*5*128
__global__ __launch_bounds__(256) void knnpq_kernel(
    const unsigned short* __restrict__ Af, const unsigned short* __restrict__ B1,
    const unsigned short* __restrict__ B2, const float* __restrict__ bias,
    unsigned short* __restrict__ PmQ, unsigned short* __restrict__ Qh,
    const _Float16* __restrict__ xef, const float* __restrict__ sqv,
    const int* __restrict__ offk, const int* __restrict__ cntk, float* __restrict__ D) {
    int bid = blockIdx.x;
    if (bid < L4_PQ_BLOCKS) {
        // -------- merged P/Q GEMM (R2-proven shape) --------
        int lin = bid;
        int b = lin & 7, pos = lin >> 3;
        int bx = pos % 6, by = pos / 6;
        int w = threadIdx.x >> 6, lane = threadIdx.x & 63;
        int sg = by * 4 + w;
        int n0 = bx * 64;
        const unsigned short* Ap = Af + (size_t)b * NN * NC + ((size_t)sg * 6 * 64 + lane) * 8;
        const unsigned short* Bp1 = B1 + ((size_t)bx * 6 * 256 + lane) * 8;
        const unsigned short* Bp2 = B2 + ((size_t)bx * 6 * 256 + lane) * 8;
        f32x4 acc1[4] = {};
        f32x4 acc2[4] = {};
#pragma unroll
        for (int kc = 0; kc < 6; ++kc) {
            s16x8 a = *(const s16x8*)(Ap + kc * 512);
#pragma unroll
            for (int c = 0; c < 4; ++c) {
                s16x8 b1 = *(const s16x8*)(Bp1 + kc * 2048 + c * 512);
                acc1[c] = __builtin_amdgcn_mfma_f32_16x16x32_bf16(a, b1, acc1[c], 0, 0, 0);
                s16x8 b2 = *(const s16x8*)(Bp2 + kc * 2048 + c * 512);
                acc2[c] = __builtin_amdgcn_mfma_f32_16x16x32_bf16(a, b2, acc2[c], 0, 0, 0);
            }
        }
        int col0 = lane & 15, rq = lane >> 4;
        unsigned short* Pb = PmQ + (size_t)b * NN * NCOUT;
        unsigned short* Qb = Qh + (size_t)b * NN * NCOUT;
#pragma unroll
        for (int r = 0; r < 4; ++r) {
            int grow = sg * 16 + rq * 4 + r;
#pragma unroll
            for (int c = 0; c < 4; ++c) {
                int col = n0 + c * 16 + col0;
                Pb[(size_t)grow * NCOUT + col] = f2bf(acc1[c][r] + bias[col]);
                Qb[(size_t)grow * NCOUT + col] = f2bf(acc2[c][r]);
            }
        }
    } else {
        // -------- Gram -> d2 tiles via fp16 MFMA --------
        int idx = bid - L4_PQ_BLOCKS;
        int b = idx & 7, pos = idx >> 3;
        int k = pos / 25, rr = pos % 25;
        int tj = rr / 5, ti = rr % 5;
        int bk = b * NK + k;
        int base = offk[bk], L = cntk[bk];
        if (ti * 64 >= L || tj * 64 >= L) return;
        int w = threadIdx.x >> 6, lane = threadIdx.x & 63;
        const _Float16* Xf = xef + (size_t)bk * (20 * 6 * 512);
        const _Float16* Ap = Xf + (((size_t)(ti * 4 + w) * 6) * 64 + lane) * 8;
        f32x4 acc[4] = {};
#pragma unroll
        for (int kc = 0; kc < 6; ++kc) {
            f16x8 a = *(const f16x8*)(Ap + kc * 512);
#pragma unroll
            for (int js = 0; js < 4; ++js) {
                f16x8 bv = *(const f16x8*)(Xf + (((size_t)(tj * 4 + js) * 6 + kc) * 64 + lane) * 8);
                acc[js] = __builtin_amdgcn_mfma_f32_16x16x32_f16(a, bv, acc[js], 0, 0, 0);
            }
        }
        float* Dr = D + (size_t)bk * DSLOT;
        const float* Sb = sqv + (size_t)b * NN + base;
        int col0 = lane & 15, rq = lane >> 4;
#pragma unroll
        for (int r = 0; r < 4; ++r) {
            int i = ti * 64 + w * 16 + rq * 4 + r;
            if (i >= L) continue;
            float si = Sb[i];
#pragma unroll
            for (int js = 0; js < 4; ++js) {
                int j = tj * 64 + js * 16 + col0;
                if (j < L) Dr[(size_t)i * DSTRIDE + j] = si + Sb[j] - 2.0f * acc[js][r];
            }
        }
    }
}

// ---------------- L5 fused: select9 (blocks 0..6271) | hcmax (6272..6399), 256 threads ----------------
#define LEXLT(da, ca, db, cb) ((da) < (db) || ((da) == (db) && (ca) < (cb)))
#define L5_SEL_BLOCKS 6272   // 784*8
#define L5_HC_BLOCKS 128
__global__ __launch_bounds__(256) void sel_kernel(const float* __restrict__ D,
                                                  const int* __restrict__ lsv,
                                                  const int* __restrict__ offk,
                                                  const int* __restrict__ cntk,
                                                  int* __restrict__ nbr,
                                                  const float* __restrict__ Pc,
                                                  const float* __restrict__ Qc,
                                                  float* __restrict__ hc) {
    int bid = blockIdx.x;
    if (bid < L5_SEL_BLOCKS) {
        // -------- top-9 selection: one wave per row --------
        int lin = bid;
        int b = lin & 7, quad = lin >> 3;
        int r = quad * 4 + (threadIdx.x >> 6);
        int lane = threadIdx.x & 63;
        int k = lsv[(size_t)b * NN + r];
        int bk = b * NK + k;
        int base = offk[bk], L = cntk[bk];
        int Lc = L < LPMAX ? L : LPMAX;
        const float* Dr = D + (size_t)bk * DSLOT + (size_t)(r - base) * DSTRIDE;
        float d0, d1, d2, d3, d4;
        int c0, c1, c2, c3, c4;
        c0 = lane;
        c1 = lane + 64;
        c2 = lane + 128;
        c3 = lane + 192;
        c4 = lane + 256;
        d0 = c0 < Lc ? Dr[c0] : FLT_INF;
        d1 = c1 < Lc ? Dr[c1] : FLT_INF;
        d2 = c2 < Lc ? Dr[c2] : FLT_INF;
        d3 = c3 < Lc ? Dr[c3] : FLT_INF;
        d4 = c4 < Lc ? Dr[c4] : FLT_INF;
#define CS(da, ca, db, cb)                  \
    if (LEXLT(db, cb, da, ca)) {            \
        float t = da; da = db; db = t;      \
        int u = ca; ca = cb; cb = u;        \
    }
        CS(d0, c0, d1, c1) CS(d3, c3, d4, c4) CS(d2, c2, d4, c4) CS(d2, c2, d3, c3)
        CS(d1, c1, d4, c4) CS(d0, c0, d3, c3) CS(d0, c0, d2, c2) CS(d1, c1, d3, c3)
        CS(d1, c1, d2, c2)
#undef CS
        size_t row = (size_t)b * NN + r;
        for (int q = 0; q < KNB; ++q) {
            float bd = d0;
            int bc = c0;
#pragma unroll
            for (int m = 32; m; m >>= 1) {
                float od = __shfl_xor(bd, m, 64);
                int oc = __shfl_xor(bc, m, 64);
                if (LEXLT(od, oc, bd, bc)) {
                    bd = od;
                    bc = oc;
                }
            }
            if (lane == 0) nbr[row * KNB + q] = base + bc;
            if (d0 == bd && c0 == bc) {
                d0 = d1; c0 = c1;
                d1 = d2; c1 = c2;
                d2 = d3; c2 = c3;
                d3 = d4; c3 = c4;
                d4 = FLT_INF; c4 = 0x7fffffff;
            }
        }
    } else {
        // -------- cluster message max (valley trick), o-strided to 256 threads --------
        int idx = bid - L5_SEL_BLOCKS;
        int bk = ((idx & 7) * NK) + (idx >> 3);  // XCD remap
        int b = bk >> 4, i = bk & 15;
        for (int o = threadIdx.x; o < NCOUT; o += 256) {
            float pi = Pc[((size_t)b * NK + i) * NCOUT + o];
            float qi = Qc[((size_t)b * NK + i) * NCOUT + o];
            float pmq = pi - qi;
            float qmn = FLT_INF, qmx = -FLT_INF;
            for (int j = 0; j < NK; ++j) {
                float v = Qc[((size_t)b * NK + j) * NCOUT + o];
                qmn = fminf(qmn, v);
                qmx = fmaxf(qmx, v);
            }
            hc[((size_t)b * NK + i) * NCOUT + o] =
                fmaxf(gelu_t(pmq + qmn), gelu_t(pmq + qmx));
        }
    }
}

// ---------------- node max + cluster term -> hn bf16 A-fragments (wide-grid gather) ----------------
__global__ __launch_bounds__(192) void hv_kernel(const unsigned short* __restrict__ PmQ,
                                                 const unsigned short* __restrict__ Qh,
                                                 const int* __restrict__ nbr,
                                                 const int* __restrict__ lsv,
                                                 const float* __restrict__ hc,
                                                 unsigned short* __restrict__ hnf) {
    int lin = (int)blockIdx.y * 784 + blockIdx.x;
    int b = lin & 7, quad = lin >> 3;
    int t = threadIdx.x;           // 192 = 4 rows x 48 channel-chunks
    int rsub = t / 48, c = t % 48;
    int i = quad * 4 + rsub;
    size_t row = (size_t)b * NN + i;
    int lab = lsv[row];
    int o0 = c * 8;
    int jn[KNB];
#pragma unroll
    for (int q = 0; q < KNB; ++q) jn[q] = nbr[row * KNB + q];
    const unsigned short* Qbb = Qh + (size_t)b * NN * NCOUT + o0;
    us8 pv = *(const us8*)(PmQ + row * NCOUT + o0);
    us8 q0 = *(const us8*)(Qbb + (size_t)jn[0] * NCOUT);
    float qmn[8], qmx[8];
#pragma unroll
    for (int e = 0; e < 8; ++e) {
        float v = bf2f(q0[e]);
        qmn[e] = v;
        qmx[e] = v;
    }
#pragma unroll
    for (int q = 1; q < KNB; ++q) {
        us8 qv = *(const us8*)(Qbb + (size_t)jn[q] * NCOUT);
#pragma unroll
        for (int e = 0; e < 8; ++e) {
            float v = bf2f(qv[e]);
            qmn[e] = fminf(qmn[e], v);
            qmx[e] = fmaxf(qmx[e], v);
        }
    }
    const float* hcr = hc + ((size_t)b * NK + lab) * NCOUT + o0;
    float4 h0 = *(const float4*)hcr;
    float4 h1 = *(const float4*)(hcr + 4);
    float hcv[8] = {h0.x, h0.y, h0.z, h0.w, h1.x, h1.y, h1.z, h1.w};
    unsigned short pack[8];
#pragma unroll
    for (int e = 0; e < 8; ++e) {
        float pmq = bf2f(pv[e]);
        float m = fmaxf(gelu_t(pmq + qmn[e]), gelu_t(pmq + qmx[e]));
        pack[e] = f2bf(m + hcv[e]);
    }
    int s = i >> 4, mm = i & 15;
    *(us8*)(hnf + (size_t)b * NN * NCOUT +
            (((size_t)s * 12 + (c >> 2)) * 64 + (c & 3) * 16 + mm) * 8) = *(const us8*)pack;
}

// ---------------- fc2: bf16 out + bias, contiguous sorted rows ----------------
template <int KC>
__global__ __launch_bounds__(256) void gemm_mfma_hb(const unsigned short* __restrict__ Af,
                                                    size_t aStride,
                                                    const unsigned short* __restrict__ Bf,
                                                    const float* __restrict__ bias,
                                                    unsigned short* __restrict__ C,
                                                    size_t cStride, int ldc) {
    int lin = ((int)blockIdx.z * 49 + blockIdx.y) * 3 + blockIdx.x;
    int b = lin & 7, pos = lin >> 3;
    int bx = pos % 3, by = pos / 3;
    int w = threadIdx.x >> 6, lane = threadIdx.x & 63;
    int sg = by * 4 + w;
    int n0 = bx * 64;
    const unsigned short* Ap = Af + (size_t)b * aStride + ((size_t)sg * KC * 64 + lane) * 8;
    const unsigned short* Bp = Bf + ((size_t)bx * KC * 256 + lane) * 8;
    f32x4 acc[4] = {};
#pragma unroll
    for (int kc = 0; kc < KC; ++kc) {
        s16x8 a = *(const s16x8*)(Ap + kc * 512);
#pragma unroll
        for (int c = 0; c < 4; ++c) {
            s16x8 bv = *(const s16x8*)(Bp + kc * 2048 + c * 512);
            acc[c] = __builtin_amdgcn_mfma_f32_16x16x32_bf16(a, bv, acc[c], 0, 0, 0);
        }
    }
    int col0 = lane & 15, rq = lane >> 4;
    unsigned short* Cb = C + (size_t)b * cStride;
#pragma unroll
    for (int r = 0; r < 4; ++r) {
        int grow = sg * 16 + rq * 4 + r;
#pragma unroll
        for (int c = 0; c < 4; ++c) {
            int col = n0 + c * 16 + col0;
            Cb[(size_t)grow * ldc + col] = f2bf(acc[c][r] + bias[col]);
        }
    }
}

// ---------------- transpose (b,n,c)->(b,c,n) + residual; row gather via mapping ----------------
__global__ void out_kernel(const unsigned short* __restrict__ T, const float* __restrict__ X,
                           const int* __restrict__ mapping, float* __restrict__ Y) {
    __shared__ float t[32][33];
    int lin = ((int)blockIdx.z * 98 + blockIdx.y) * 6 + blockIdx.x;
    int b = lin & 7, pos = lin >> 3;
    int c0 = (pos % 6) * 32, n0 = (pos / 6) * 32;
    int tx = threadIdx.x, ty = threadIdx.y;  // 32 x 8
#pragma unroll
    for (int q = 0; q < 4; ++q) {
        int n = n0 + ty + q * 8;
        int srow = mapping[(size_t)b * NN + n];
        t[ty + q * 8][tx] = bf2f(T[((size_t)b * NN + srow) * NC + c0 + tx]);
    }
    __syncthreads();
#pragma unroll
    for (int q = 0; q < 4; ++q) {
        int c = c0 + ty + q * 8;
        size_t idx = ((size_t)b * NC + c) * NN + n0 + tx;
        Y[idx] = t[tx][ty + q * 8] + X[idx];
    }
}

extern "C" void kernel_launch(void* const* d_in, const int* in_sizes, int n_in, void* d_out,
                              int out_size, void* d_ws, size_t ws_size, hipStream_t stream) {
    const float* x = (const float*)d_in[0];
    const int* labels = (const int*)d_in[1];
    const float* cpe_w = (const float*)d_in[2];
    const float* cpe_b = (const float*)d_in[3];
    const float* fc1_w = (const float*)d_in[4];
    const float* fc1_b = (const float*)d_in[5];
    const float* nn_v_w = (const float*)d_in[6];
    const float* nn_v_b = (const float*)d_in[7];
    const float* nn_c_w = (const float*)d_in[8];
    const float* nn_c_b = (const float*)d_in[9];
    const float* fc2_w = (const float*)d_in[10];
    const float* fc2_b = (const float*)d_in[11];
    float* out = (float*)d_out;

    const size_t SZ_XS = (size_t)NB * NN * NC;
    const size_t SZ_P = (size_t)NB * NN * NCOUT;
    const size_t BN = (size_t)NB * NN;
    const size_t SZ_CEN = (size_t)NB * NK * NC;
    const size_t SZ_PC = (size_t)NB * NK * NCOUT;

    float* base = (float*)d_ws;
    float* xs = base;                 // sorted fc1 out (fp32); reused as bf16 out_t later
    float* xpeRegion = xs + SZ_XS;    // bf16 conv out (ushort)
    float* Pb = xpeRegion + SZ_XS;    // bf16 PmQ (sorted) — no longer aliases D
    float* Qb = Pb + SZ_P;            // bf16 Qh (sorted)
    float* rinv = Qb + SZ_P;          // unused slot (layout stability)
    float* sqv = rinv + BN;
    float* cen = sqv + BN;            // unused (centroid in LDS), layout kept
    float* Pc = cen + SZ_CEN;
    float* Qc = Pc + SZ_PC;
    float* hcv = Qc + SZ_PC;
    int* order = (int*)(hcv + SZ_PC);
    int* mapping = order + BN;
    int* lsv = mapping + BN;
    int* nbrv = lsv + BN;
    int* cntk = nbrv + BN * KNB;
    int* offk = cntk + NB * NK;
    unsigned short* xpe = (unsigned short*)xpeRegion;
    unsigned short* PmQh = (unsigned short*)Pb;
    unsigned short* Qh = (unsigned short*)Qb;
    unsigned short* out_t = (unsigned short*)xs;  // xs fp32 dead after L3 (xe+cenpq)
    unsigned short* frag = (unsigned short*)(offk + NB * NK);
    unsigned short* hn_frag = frag;               // slot 0: hn fragments (hv -> fc2)
    unsigned short* xs_frag = frag + SZ_XS;
    unsigned short* wf1 = frag + 2 * SZ_XS;
    unsigned short* wfpmq = wf1 + (size_t)NC * NC;    // (Wtop-Wbot) 192x384
    unsigned short* wfq = wfpmq + (size_t)NC * NCOUT; // Wbot 192x384
    unsigned short* wf2 = wfq + (size_t)NC * NCOUT;
    _Float16* xef = (_Float16*)(wf2 + (size_t)NCOUT * NC);
    // D moved OUT of the Pb alias (enables pq || gram overlap). 52.4MB; total ws
    // usage ~206MB < 256MiB workspace (harness fill shows 262144KB poison).
    float* Dbuf = (float*)(xef + (size_t)(NB * NK) * (20 * 6 * 512));

    // L1: conv | order | wcvt
    front_kernel<<<FRONT_CONV_BLOCKS + FRONT_ORDER_BLOCKS + FRONT_WCVT_BLOCKS, 256, 0, stream>>>(
        x, cpe_w, cpe_b, xpe, labels, order, mapping, lsv, cntk, offk, fc1_w, nn_v_w, fc2_w,
        wf1, wfpmq, wfq, wf2);
    // L2: fc1 fused with transpose
    fc1_kernel<<<NB * (NN / 64), 256, 0, stream>>>(xpe, wf1, fc1_b, xs, xs_frag, mapping);
    // L3: xe_cvt | cenpq (both depend only on xs)
    mid_kernel<<<MID_XE_BLOCKS + MID_CEN_BLOCKS, 384, 0, stream>>>(
        xs, offk, cntk, xef, sqv, nn_c_w, nn_c_b, Pc, Qc);
    // L4: pq GEMM | gram (independent now that D is un-aliased)
    knnpq_kernel<<<L4_PQ_BLOCKS + L4_GRAM_BLOCKS, 256, 0, stream>>>(
        xs_frag, wfpmq, wfq, nn_v_b, PmQh, Qh, xef, sqv, offk, cntk, Dbuf);
    // L5: select9 | hcmax
    sel_kernel<<<L5_SEL_BLOCKS + L5_HC_BLOCKS, 256, 0, stream>>>(
        Dbuf, lsv, offk, cntk, nbrv, Pc, Qc, hcv);
    // L6: hv wide-grid gather (R3 lesson: keep gather TLP)
    hv_kernel<<<dim3(NN / 4, NB), 192, 0, stream>>>(PmQh, Qh, nbrv, lsv, hcv, hn_frag);
    // L7: fc2 contiguous sorted rows
    gemm_mfma_hb<12><<<dim3(NC / 64, NN / 64, NB), 256, 0, stream>>>(
        hn_frag, SZ_P / NB, wf2, fc2_b, out_t, (size_t)NN * NC, NC);
    // L8: transpose + residual
    out_kernel<<<dim3(NC / 32, NN / 32, NB), dim3(32, 8), 0, stream>>>(out_t, x, mapping, out);
}

// Round 8
// 263.007 us; speedup vs baseline: 1.2615x; 1.0167x over previous
//
#include <hip/hip_runtime.h>
#include <math.h>

#define NB 8
#define NC 192
#define NH 56
#define NW 56
#define NN 3136      // NH*NW
#define NK 16        // clusters
#define KNB 9        // neighbors
#define NCOUT 384    // 2*NC
#define LPMAX 320    // max padded cluster size (L~196±14, 320 is >8 sigma)
#define DSTRIDE 320
#define DSLOT (320 * 320)

#define FLT_INF __builtin_inff()

typedef short s16x8 __attribute__((ext_vector_type(8)));
typedef _Float16 f16x8 __attribute__((ext_vector_type(8)));
typedef float f32x4 __attribute__((ext_vector_type(4)));
typedef float f32x2 __attribute__((ext_vector_type(2)));
typedef unsigned short us8 __attribute__((ext_vector_type(8)));
typedef unsigned short us4 __attribute__((ext_vector_type(4)));

// gelu(tanh approx) via exact sigmoid identity: 0.5*(1+tanh(u)) = 1/(1+exp(-2u)).
__device__ __forceinline__ float gelu_t(float x) {
    const float k0 = 0.7978845608028654f;
    float u = k0 * (x + 0.044715f * x * x * x);
    float sg = __builtin_amdgcn_rcpf(1.0f + __expf(-2.0f * u));
    return x * sg;
}

__device__ __forceinline__ unsigned short f2bf(float f) {
    unsigned u = __float_as_uint(f);
    u += 0x7fff + ((u >> 16) & 1);  // round-to-nearest-even
    return (unsigned short)(u >> 16);
}

__device__ __forceinline__ float bf2f(unsigned short h) {
    return __uint_as_float(((unsigned)h) << 16);
}

// ============================================================================
// XCD batch-affinity (T1, batch-per-XCD): lin%8 = batch pins batch b's whole
// pipeline to XCD b; producer->consumer intermediates stay in its 4MiB L2.
// LESSON (R3): never fuse latency-bound gathers into compute-tile-shaped
// kernels (fc2hv: 71µs @ 15% occ). LESSON (R4): never grow accumulators past
// ~48 VGPRs in streaming fragment-GEMMs (pq2: 85µs @ MfmaUtil 3%).
// LESSON (R6/R7): serialization was ~70µs — horizontal fusion (8 launches)
// recovered ~11µs; verified. R8: conv branch was LDS-ISSUE-bound (119 scalar
// ds_read/iter incl. 49 in-loop weight broadcasts) — weights hoisted to regs,
// tile stride padded to 64 for float4 LDS reads, f32x2 packed FMA. Bit-exact.
// ============================================================================

// ---------------- fused front kernel: conv (blocks 0..1535) | order | wcvt
#define FRONT_CONV_BLOCKS (NB * NC)            // 1536
#define FRONT_ORDER_BLOCKS (NB * NK)           // 128
#define FRONT_WCVT_BLOCKS 288                  // 6*12*4
__global__ __launch_bounds__(256) void front_kernel(
    const float* __restrict__ X, const float* __restrict__ W7, const float* __restrict__ bias,
    unsigned short* __restrict__ xpe,
    const int* __restrict__ labels, int* __restrict__ order, int* __restrict__ mapping,
    int* __restrict__ lsv, int* __restrict__ cntk, int* __restrict__ offk,
    const float* __restrict__ Wf1, const float* __restrict__ Wv, const float* __restrict__ Wf2,
    unsigned short* __restrict__ wf1, unsigned short* __restrict__ wfpmq,
    unsigned short* __restrict__ wfq, unsigned short* __restrict__ wf2) {
    __shared__ float tile[62 * 64];  // stride 64: (y+dy)*64 + x0 is 16B-aligned (x0%4==0)
    __shared__ float wl[49];
    int bid = blockIdx.x;
    int tid = threadIdx.x;
    if (bid < FRONT_CONV_BLOCKS) {
        // -------- depthwise 7x7 conv + bias + residual -> bf16 xpe --------
        int bc = (bid & 7) * NC + (bid >> 3);  // XCD remap: batch = bid%8
        int c = bc % NC;
        const float* Xp = X + (size_t)bc * NN;
        if (tid < 49) wl[tid] = W7[(size_t)c * 49 + tid];
        for (int idx = tid; idx < 62 * 62; idx += 256) {
            int ty = idx / 62, tx = idx % 62;
            int gy = ty - 3, gx = tx - 3;
            float v = 0.0f;
            if (gy >= 0 && gy < NH && gx >= 0 && gx < NW) v = Xp[gy * NW + gx];
            tile[ty * 64 + tx] = v;
        }
        __syncthreads();
        // hoist all 49 weights to registers: zero in-loop wl LDS traffic
        float wreg[49];
#pragma unroll
        for (int i = 0; i < 49; ++i) wreg[i] = wl[i];
        float cb = bias[c];
        for (int g = tid; g < (NN / 4); g += 256) {
            int y = g / (NW / 4), x0 = (g % (NW / 4)) * 4;
            f32x2 a01 = {0.0f, 0.0f};
            f32x2 a23 = {0.0f, 0.0f};
#pragma unroll
            for (int dy = 0; dy < 7; ++dy) {
                const float* tr = &tile[(y + dy) * 64 + x0];
                float4 rA = *(const float4*)tr;        // taps 0..3  (16B aligned)
                float4 rB = *(const float4*)(tr + 4);  // taps 4..7
                float2 rC = *(const float2*)(tr + 8);  // taps 8..9  (8B aligned)
                float r[10] = {rA.x, rA.y, rA.z, rA.w, rB.x, rB.y, rB.z, rB.w, rC.x, rC.y};
#pragma unroll
                for (int dx = 0; dx < 7; ++dx) {
                    float wv = wreg[dy * 7 + dx];
                    f32x2 va = {r[dx], r[dx + 1]};
                    f32x2 vb = {r[dx + 2], r[dx + 3]};
                    a01 += va * wv;  // v_pk_fma_f32: two IEEE FMAs, same order as scalar
                    a23 += vb * wv;
                }
            }
            const float* rr = &tile[(y + 3) * 64 + x0 + 3];
            us4 o;
            o[0] = f2bf(a01.x + cb + rr[0]);
            o[1] = f2bf(a01.y + cb + rr[1]);
            o[2] = f2bf(a23.x + cb + rr[2]);
            o[3] = f2bf(a23.y + cb + rr[3]);
            *(us4*)(xpe + (size_t)bc * NN + y * NW + x0) = o;
        }
    } else if (bid < FRONT_CONV_BLOCKS + FRONT_ORDER_BLOCKS) {
        if (tid >= 64) return;
        int idx = bid - FRONT_CONV_BLOCKS;
        int b = idx >> 4;
        int k = idx & 15;
        int lane = tid;
        const int* lb = labels + (size_t)b * NN;
        int cntLess = 0, cntEq = 0;
        for (int n0 = 0; n0 < NN; n0 += 64) {
            int lab = lb[n0 + lane] & 15;
            cntLess += __popcll(__ballot(lab < k));
            cntEq += __popcll(__ballot(lab == k));
        }
        int base = cntLess;
        int run = 0;
        for (int n0 = 0; n0 < NN; n0 += 64) {
            int n = n0 + lane;
            int lab = lb[n] & 15;
            bool p = (lab == k);
            unsigned long long mask = __ballot(p);
            int rank = __popcll(mask & ((1ull << lane) - 1ull));
            if (p) {
                int pos = base + run + rank;
                order[b * NN + pos] = n;
                mapping[b * NN + n] = pos;
                lsv[b * NN + pos] = k;
            }
            run += __popcll(mask);
        }
        if (lane == 0) {
            offk[b * NK + k] = base;
            cntk[b * NK + k] = cntEq;
        }
    } else {
        int u = bid - (FRONT_CONV_BLOCKS + FRONT_ORDER_BLOCKS);
        int nt = u % 6, kc = (u / 6) % 12, z = u / 72;
        const float* W;
        unsigned short* Bf;
        int ldw, rowoff, KC, NT;
        bool diff = false;
        if (z == 0) { W = Wf1; Bf = wf1; ldw = NC; rowoff = 0; KC = 6; NT = 3; }
        else if (z == 1) { W = Wv; Bf = wfpmq; ldw = NCOUT; rowoff = 0; KC = 6; NT = 6; diff = true; }
        else if (z == 2) { W = Wv; Bf = wfq; ldw = NCOUT; rowoff = NC; KC = 6; NT = 6; }
        else { W = Wf2; Bf = wf2; ldw = NC; rowoff = 0; KC = 12; NT = 3; }
        if (nt >= NT || kc >= KC) return;
        int c = tid >> 6, l = tid & 63;
        int n = l & 15, q = l >> 4;
        int col = nt * 64 + c * 16 + n;
        int krow = rowoff + kc * 32 + q * 8;
        unsigned short pack[8];
#pragma unroll
        for (int j = 0; j < 8; ++j) {
            float v = W[(size_t)(krow + j) * ldw + col];
            if (diff) v -= W[(size_t)(NC + krow + j) * ldw + col];
            pack[j] = f2bf(v);
        }
        *(us8*)(Bf + ((((size_t)nt * KC + kc) * 4 + c) * 64 + l) * 8) = *(const us8*)pack;
    }
}

// ---------------- fc1 fused with transpose (verified win; acc[12]=48 regs ceiling) ----------------
__global__ __launch_bounds__(256) void fc1_kernel(const unsigned short* __restrict__ xpe,
                                                  const unsigned short* __restrict__ Bf,
                                                  const float* __restrict__ bias,
                                                  float* __restrict__ xs,
                                                  unsigned short* __restrict__ Cfrag,
                                                  const int* __restrict__ rowmap) {
    int lin = blockIdx.x;              // 392 = 49*8
    int b = lin & 7, by = lin >> 3;
    int w = threadIdx.x >> 6, lane = threadIdx.x & 63;
    int sg = by * 4 + w;
    int m = lane & 15, q = lane >> 4;
    int n = by * 64 + w * 16 + m;
    const unsigned short* Xb = xpe + (size_t)b * NC * NN + n;
    f32x4 acc[12] = {};
#pragma unroll
    for (int kc = 0; kc < 6; ++kc) {
        int ch = kc * 32 + q * 8;
        s16x8 a;
#pragma unroll
        for (int j = 0; j < 8; ++j) a[j] = (short)Xb[(size_t)(ch + j) * NN];
#pragma unroll
        for (int ct = 0; ct < 12; ++ct) {
            s16x8 bv = *(const s16x8*)(Bf + ((((size_t)(ct >> 2) * 6 + kc) * 4 + (ct & 3)) * 64 + lane) * 8);
            acc[ct] = __builtin_amdgcn_mfma_f32_16x16x32_bf16(a, bv, acc[ct], 0, 0, 0);
        }
    }
    float* Cb = xs + (size_t)b * NN * NC;
#pragma unroll
    for (int r = 0; r < 4; ++r) {
        int grow = sg * 16 + q * 4 + r;
        int orow = rowmap[(size_t)b * NN + grow];
        int s2 = orow >> 4, m2 = orow & 15;
#pragma unroll
        for (int ct = 0; ct < 12; ++ct) {
            int col = ct * 16 + m;
            float v = acc[ct][r] + bias[col];
            Cb[(size_t)orow * NC + col] = v;
            int kc2 = col >> 5, q2 = (col >> 3) & 3, j2 = col & 7;
            Cfrag[(size_t)b * NN * NC + (((size_t)s2 * 6 + kc2) * 64 + q2 * 16 + m2) * 8 + j2] =
                f2bf(v);
        }
    }
}

// ---------------- L3 fused: xe_cvt (blocks 0..2559) | cenpq (2560..2687), 384 threads ----------------
#define MID_XE_BLOCKS 2560   // 20*16*8
#define MID_CEN_BLOCKS 128
__global__ __launch_bounds__(384) void mid_kernel(const float* __restrict__ xs,
                                                  const int* __restrict__ offk,
                                                  const int* __restrict__ cntk,
                                                  _Float16* __restrict__ xef,
                                                  float* __restrict__ sqv,
                                                  const float* __restrict__ Wc,
                                                  const float* __restrict__ bc,
                                                  float* __restrict__ Pc,
                                                  float* __restrict__ Qc) {
    __shared__ float psum[16][25];
    __shared__ float rloc[16];
    __shared__ float part[4][NC];
    __shared__ float ce[NC];
    int bid = blockIdx.x;
    if (bid < MID_XE_BLOCKS) {
        // -------- xe = xs*rinv -> fp16 A-fragments; rinv + sqv in-kernel --------
        int lin = bid;
        int b = lin & 7, pos = lin >> 3;
        int k = pos / 20, strip = pos % 20;
        int bk = b * NK + k;
        int base = offk[bk], L = cntk[bk];
        if (strip * 16 >= L) return;
        int kc = threadIdx.x >> 6, l = threadIdx.x & 63;
        int m = l & 15, q = l >> 4;
        int rl = strip * 16 + m;
        int row = base + (rl < L ? rl : L - 1);
        const float* src = xs + ((size_t)b * NN + row) * NC + kc * 32 + q * 8;
        float4 v0 = *(const float4*)src;
        float4 v1 = *(const float4*)(src + 4);
        float part2 = v0.x * v0.x + v0.y * v0.y + v0.z * v0.z + v0.w * v0.w + v1.x * v1.x +
                      v1.y * v1.y + v1.z * v1.z + v1.w * v1.w;
        psum[m][kc * 4 + q] = part2;
        __syncthreads();
        if (threadIdx.x < 16) {
            float s = 0.0f;
#pragma unroll
            for (int i2 = 0; i2 < 24; ++i2) s += psum[threadIdx.x][i2];
            float nrm = fmaxf(sqrtf(s), 1e-12f);
            float ri = 1.0f / nrm;
            rloc[threadIdx.x] = ri;
            if (strip * 16 + (int)threadIdx.x < L)
                sqv[(size_t)b * NN + base + strip * 16 + threadIdx.x] = (s * ri) * ri;
        }
        __syncthreads();
        float rv = rloc[m];
        f16x8 pack;
        pack[0] = (_Float16)(v0.x * rv);
        pack[1] = (_Float16)(v0.y * rv);
        pack[2] = (_Float16)(v0.z * rv);
        pack[3] = (_Float16)(v0.w * rv);
        pack[4] = (_Float16)(v1.x * rv);
        pack[5] = (_Float16)(v1.y * rv);
        pack[6] = (_Float16)(v1.z * rv);
        pack[7] = (_Float16)(v1.w * rv);
        *(f16x8*)(xef + (size_t)bk * (20 * 6 * 512) + (((size_t)strip * 6 + kc) * 64 + l) * 8) =
            pack;
    } else {
        // -------- centroids + cluster P/Q (bit-exact 384-thread form) --------
        int idx = bid - MID_XE_BLOCKS;
        int bk = ((idx & 7) * NK) + (idx >> 3);  // XCD remap
        int b = bk >> 4;
        int base = offk[bk], L = cntk[bk];
        int c = threadIdx.x % NC;
        int w2 = threadIdx.x / NC;  // 0..1; this thread covers partitions w2 and w2+2
        const float* Xb = xs + ((size_t)b * NN + base) * NC + c;
        float s0 = 0.0f, s1 = 0.0f;
        for (int r = w2; r < L; r += 4) s0 += Xb[(size_t)r * NC];
        for (int r = w2 + 2; r < L; r += 4) s1 += Xb[(size_t)r * NC];
        part[w2][c] = s0;
        part[w2 + 2][c] = s1;
        __syncthreads();
        if (threadIdx.x < NC) {
            int cc = threadIdx.x;
            float tot = part[0][cc] + part[1][cc] + part[2][cc] + part[3][cc];
            ce[cc] = tot / fmaxf((float)L, 1.0f);
        }
        __syncthreads();
        int o = threadIdx.x;  // 0..383
        float pcA = 0.0f, qcA = 0.0f, pcB = 0.0f, qcB = 0.0f;
        for (int c2 = 0; c2 < 96; ++c2) {
            float cv = ce[c2];
            pcA += cv * Wc[(size_t)c2 * NCOUT + o];
            qcA += cv * Wc[(size_t)(NC + c2) * NCOUT + o];
        }
        for (int c2 = 96; c2 < 192; ++c2) {
            float cv = ce[c2];
            pcB += cv * Wc[(size_t)c2 * NCOUT + o];
            qcB += cv * Wc[(size_t)(NC + c2) * NCOUT + o];
        }
        Pc[(size_t)bk * NCOUT + o] = pcA + pcB + bc[o];
        Qc[(size_t)bk * NCOUT + o] = qcA + qcB;
    }
}

// ---------------- L4 fused: pq GEMM (blocks 0..2351) | gram (2352..5551), 256 threads ----------------
#define L4_PQ_BLOCKS 2352    // 6*49*8
#define L4_GRAM_BLOCKS 3200  // 5*5*128
__global__ __launch_bounds__(256) void knnpq_kernel(
    const unsigned short* __restrict__ Af, const unsigned short* __restrict__ B1,
    const unsigned short* __restrict__ B2, const float* __restrict__ bias,
    unsigned short* __restrict__ PmQ, unsigned short* __restrict__ Qh,
    const _Float16* __restrict__ xef, const float* __restrict__ sqv,
    const int* __restrict__ offk, const int* __restrict__ cntk, float* __restrict__ D) {
    int bid = blockIdx.x;
    if (bid < L4_PQ_BLOCKS) {
        // -------- merged P/Q GEMM (R2-proven shape) --------
        int lin = bid;
        int b = lin & 7, pos = lin >> 3;
        int bx = pos % 6, by = pos / 6;
        int w = threadIdx.x >> 6, lane = threadIdx.x & 63;
        int sg = by * 4 + w;
        int n0 = bx * 64;
        const unsigned short* Ap = Af + (size_t)b * NN * NC + ((size_t)sg * 6 * 64 + lane) * 8;
        const unsigned short* Bp1 = B1 + ((size_t)bx * 6 * 256 + lane) * 8;
        const unsigned short* Bp2 = B2 + ((size_t)bx * 6 * 256 + lane) * 8;
        f32x4 acc1[4] = {};
        f32x4 acc2[4] = {};
#pragma unroll
        for (int kc = 0; kc < 6; ++kc) {
            s16x8 a = *(const s16x8*)(Ap + kc * 512);
#pragma unroll
            for (int c = 0; c < 4; ++c) {
                s16x8 b1 = *(const s16x8*)(Bp1 + kc * 2048 + c * 512);
                acc1[c] = __builtin_amdgcn_mfma_f32_16x16x32_bf16(a, b1, acc1[c], 0, 0, 0);
                s16x8 b2 = *(const s16x8*)(Bp2 + kc * 2048 + c * 512);
                acc2[c] = __builtin_amdgcn_mfma_f32_16x16x32_bf16(a, b2, acc2[c], 0, 0, 0);
            }
        }
        int col0 = lane & 15, rq = lane >> 4;
        unsigned short* Pb = PmQ + (size_t)b * NN * NCOUT;
        unsigned short* Qb = Qh + (size_t)b * NN * NCOUT;
#pragma unroll
        for (int r = 0; r < 4; ++r) {
            int grow = sg * 16 + rq * 4 + r;
#pragma unroll
            for (int c = 0; c < 4; ++c) {
                int col = n0 + c * 16 + col0;
                Pb[(size_t)grow * NCOUT + col] = f2bf(acc1[c][r] + bias[col]);
                Qb[(size_t)grow * NCOUT + col] = f2bf(acc2[c][r]);
            }
        }
    } else {
        // -------- Gram -> d2 tiles via fp16 MFMA --------
        int idx = bid - L4_PQ_BLOCKS;
        int b = idx & 7, pos = idx >> 3;
        int k = pos / 25, rr = pos % 25;
        int tj = rr / 5, ti = rr % 5;
        int bk = b * NK + k;
        int base = offk[bk], L = cntk[bk];
        if (ti * 64 >= L || tj * 64 >= L) return;
        int w = threadIdx.x >> 6, lane = threadIdx.x & 63;
        const _Float16* Xf = xef + (size_t)bk * (20 * 6 * 512);
        const _Float16* Ap = Xf + (((size_t)(ti * 4 + w) * 6) * 64 + lane) * 8;
        f32x4 acc[4] = {};
#pragma unroll
        for (int kc = 0; kc < 6; ++kc) {
            f16x8 a = *(const f16x8*)(Ap + kc * 512);
#pragma unroll
            for (int js = 0; js < 4; ++js) {
                f16x8 bv = *(const f16x8*)(Xf + (((size_t)(tj * 4 + js) * 6 + kc) * 64 + lane) * 8);
                acc[js] = __builtin_amdgcn_mfma_f32_16x16x32_f16(a, bv, acc[js], 0, 0, 0);
            }
        }
        float* Dr = D + (size_t)bk * DSLOT;
        const float* Sb = sqv + (size_t)b * NN + base;
        int col0 = lane & 15, rq = lane >> 4;
#pragma unroll
        for (int r = 0; r < 4; ++r) {
            int i = ti * 64 + w * 16 + rq * 4 + r;
            if (i >= L) continue;
            float si = Sb[i];
#pragma unroll
            for (int js = 0; js < 4; ++js) {
                int j = tj * 64 + js * 16 + col0;
                if (j < L) Dr[(size_t)i * DSTRIDE + j] = si + Sb[j] - 2.0f * acc[js][r];
            }
        }
    }
}

// ---------------- L5 fused: select9 (blocks 0..6271) | hcmax (6272..6399), 256 threads ----------------
#define LEXLT(da, ca, db, cb) ((da) < (db) || ((da) == (db) && (ca) < (cb)))
#define L5_SEL_BLOCKS 6272   // 784*8
#define L5_HC_BLOCKS 128
__global__ __launch_bounds__(256) void sel_kernel(const float* __restrict__ D,
                                                  const int* __restrict__ lsv,
                                                  const int* __restrict__ offk,
                                                  const int* __restrict__ cntk,
                                                  int* __restrict__ nbr,
                                                  const float* __restrict__ Pc,
                                                  const float* __restrict__ Qc,
                                                  float* __restrict__ hc) {
    int bid = blockIdx.x;
    if (bid < L5_SEL_BLOCKS) {
        // -------- top-9 selection: one wave per row --------
        int lin = bid;
        int b = lin & 7, quad = lin >> 3;
        int r = quad * 4 + (threadIdx.x >> 6);
        int lane = threadIdx.x & 63;
        int k = lsv[(size_t)b * NN + r];
        int bk = b * NK + k;
        int base = offk[bk], L = cntk[bk];
        int Lc = L < LPMAX ? L : LPMAX;
        const float* Dr = D + (size_t)bk * DSLOT + (size_t)(r - base) * DSTRIDE;
        float d0, d1, d2, d3, d4;
        int c0, c1, c2, c3, c4;
        c0 = lane;
        c1 = lane + 64;
        c2 = lane + 128;
        c3 = lane + 192;
        c4 = lane + 256;
        d0 = c0 < Lc ? Dr[c0] : FLT_INF;
        d1 = c1 < Lc ? Dr[c1] : FLT_INF;
        d2 = c2 < Lc ? Dr[c2] : FLT_INF;
        d3 = c3 < Lc ? Dr[c3] : FLT_INF;
        d4 = c4 < Lc ? Dr[c4] : FLT_INF;
#define CS(da, ca, db, cb)                  \
    if (LEXLT(db, cb, da, ca)) {            \
        float t = da; da = db; db = t;      \
        int u = ca; ca = cb; cb = u;        \
    }
        CS(d0, c0, d1, c1) CS(d3, c3, d4, c4) CS(d2, c2, d4, c4) CS(d2, c2, d3, c3)
        CS(d1, c1, d4, c4) CS(d0, c0, d3, c3) CS(d0, c0, d2, c2) CS(d1, c1, d3, c3)
        CS(d1, c1, d2, c2)
#undef CS
        size_t row = (size_t)b * NN + r;
        for (int q = 0; q < KNB; ++q) {
            float bd = d0;
            int bc = c0;
#pragma unroll
            for (int m = 32; m; m >>= 1) {
                float od = __shfl_xor(bd, m, 64);
                int oc = __shfl_xor(bc, m, 64);
                if (LEXLT(od, oc, bd, bc)) {
                    bd = od;
                    bc = oc;
                }
            }
            if (lane == 0) nbr[row * KNB + q] = base + bc;
            if (d0 == bd && c0 == bc) {
                d0 = d1; c0 = c1;
                d1 = d2; c1 = c2;
                d2 = d3; c2 = c3;
                d3 = d4; c3 = c4;
                d4 = FLT_INF; c4 = 0x7fffffff;
            }
        }
    } else {
        // -------- cluster message max (valley trick), o-strided to 256 threads --------
        int idx = bid - L5_SEL_BLOCKS;
        int bk = ((idx & 7) * NK) + (idx >> 3);  // XCD remap
        int b = bk >> 4, i = bk & 15;
        for (int o = threadIdx.x; o < NCOUT; o += 256) {
            float pi = Pc[((size_t)b * NK + i) * NCOUT + o];
            float qi = Qc[((size_t)b * NK + i) * NCOUT + o];
            float pmq = pi - qi;
            float qmn = FLT_INF, qmx = -FLT_INF;
            for (int j = 0; j < NK; ++j) {
                float v = Qc[((size_t)b * NK + j) * NCOUT + o];
                qmn = fminf(qmn, v);
                qmx = fmaxf(qmx, v);
            }
            hc[((size_t)b * NK + i) * NCOUT + o] =
                fmaxf(gelu_t(pmq + qmn), gelu_t(pmq + qmx));
        }
    }
}

// ---------------- node max + cluster term -> hn bf16 A-fragments (wide-grid gather) ----------------
__global__ __launch_bounds__(192) void hv_kernel(const unsigned short* __restrict__ PmQ,
                                                 const unsigned short* __restrict__ Qh,
                                                 const int* __restrict__ nbr,
                                                 const int* __restrict__ lsv,
                                                 const float* __restrict__ hc,
                                                 unsigned short* __restrict__ hnf) {
    int lin = (int)blockIdx.y * 784 + blockIdx.x;
    int b = lin & 7, quad = lin >> 3;
    int t = threadIdx.x;           // 192 = 4 rows x 48 channel-chunks
    int rsub = t / 48, c = t % 48;
    int i = quad * 4 + rsub;
    size_t row = (size_t)b * NN + i;
    int lab = lsv[row];
    int o0 = c * 8;
    int jn[KNB];
#pragma unroll
    for (int q = 0; q < KNB; ++q) jn[q] = nbr[row * KNB + q];
    const unsigned short* Qbb = Qh + (size_t)b * NN * NCOUT + o0;
    us8 pv = *(const us8*)(PmQ + row * NCOUT + o0);
    us8 q0 = *(const us8*)(Qbb + (size_t)jn[0] * NCOUT);
    float qmn[8], qmx[8];
#pragma unroll
    for (int e = 0; e < 8; ++e) {
        float v = bf2f(q0[e]);
        qmn[e] = v;
        qmx[e] = v;
    }
#pragma unroll
    for (int q = 1; q < KNB; ++q) {
        us8 qv = *(const us8*)(Qbb + (size_t)jn[q] * NCOUT);
#pragma unroll
        for (int e = 0; e < 8; ++e) {
            float v = bf2f(qv[e]);
            qmn[e] = fminf(qmn[e], v);
            qmx[e] = fmaxf(qmx[e], v);
        }
    }
    const float* hcr = hc + ((size_t)b * NK + lab) * NCOUT + o0;
    float4 h0 = *(const float4*)hcr;
    float4 h1 = *(const float4*)(hcr + 4);
    float hcv[8] = {h0.x, h0.y, h0.z, h0.w, h1.x, h1.y, h1.z, h1.w};
    unsigned short pack[8];
#pragma unroll
    for (int e = 0; e < 8; ++e) {
        float pmq = bf2f(pv[e]);
        float m = fmaxf(gelu_t(pmq + qmn[e]), gelu_t(pmq + qmx[e]));
        pack[e] = f2bf(m + hcv[e]);
    }
    int s = i >> 4, mm = i & 15;
    *(us8*)(hnf + (size_t)b * NN * NCOUT +
            (((size_t)s * 12 + (c >> 2)) * 64 + (c & 3) * 16 + mm) * 8) = *(const us8*)pack;
}

// ---------------- fc2: bf16 out + bias, contiguous sorted rows ----------------
template <int KC>
__global__ __launch_bounds__(256) void gemm_mfma_hb(const unsigned short* __restrict__ Af,
                                                    size_t aStride,
                                                    const unsigned short* __restrict__ Bf,
                                                    const float* __restrict__ bias,
                                                    unsigned short* __restrict__ C,
                                                    size_t cStride, int ldc) {
    int lin = ((int)blockIdx.z * 49 + blockIdx.y) * 3 + blockIdx.x;
    int b = lin & 7, pos = lin >> 3;
    int bx = pos % 3, by = pos / 3;
    int w = threadIdx.x >> 6, lane = threadIdx.x & 63;
    int sg = by * 4 + w;
    int n0 = bx * 64;
    const unsigned short* Ap = Af + (size_t)b * aStride + ((size_t)sg * KC * 64 + lane) * 8;
    const unsigned short* Bp = Bf + ((size_t)bx * KC * 256 + lane) * 8;
    f32x4 acc[4] = {};
#pragma unroll
    for (int kc = 0; kc < KC; ++kc) {
        s16x8 a = *(const s16x8*)(Ap + kc * 512);
#pragma unroll
        for (int c = 0; c < 4; ++c) {
            s16x8 bv = *(const s16x8*)(Bp + kc * 2048 + c * 512);
            acc[c] = __builtin_amdgcn_mfma_f32_16x16x32_bf16(a, bv, acc[c], 0, 0, 0);
        }
    }
    int col0 = lane & 15, rq = lane >> 4;
    unsigned short* Cb = C + (size_t)b * cStride;
#pragma unroll
    for (int r = 0; r < 4; ++r) {
        int grow = sg * 16 + rq * 4 + r;
#pragma unroll
        for (int c = 0; c < 4; ++c) {
            int col = n0 + c * 16 + col0;
            Cb[(size_t)grow * ldc + col] = f2bf(acc[c][r] + bias[col]);
        }
    }
}

// ---------------- transpose (b,n,c)->(b,c,n) + residual; row gather via mapping ----------------
__global__ void out_kernel(const unsigned short* __restrict__ T, const float* __restrict__ X,
                           const int* __restrict__ mapping, float* __restrict__ Y) {
    __shared__ float t[32][33];
    int lin = ((int)blockIdx.z * 98 + blockIdx.y) * 6 + blockIdx.x;
    int b = lin & 7, pos = lin >> 3;
    int c0 = (pos % 6) * 32, n0 = (pos / 6) * 32;
    int tx = threadIdx.x, ty = threadIdx.y;  // 32 x 8
#pragma unroll
    for (int q = 0; q < 4; ++q) {
        int n = n0 + ty + q * 8;
        int srow = mapping[(size_t)b * NN + n];
        t[ty + q * 8][tx] = bf2f(T[((size_t)b * NN + srow) * NC + c0 + tx]);
    }
    __syncthreads();
#pragma unroll
    for (int q = 0; q < 4; ++q) {
        int c = c0 + ty + q * 8;
        size_t idx = ((size_t)b * NC + c) * NN + n0 + tx;
        Y[idx] = t[tx][ty + q * 8] + X[idx];
    }
}

extern "C" void kernel_launch(void* const* d_in, const int* in_sizes, int n_in, void* d_out,
                              int out_size, void* d_ws, size_t ws_size, hipStream_t stream) {
    const float* x = (const float*)d_in[0];
    const int* labels = (const int*)d_in[1];
    const float* cpe_w = (const float*)d_in[2];
    const float* cpe_b = (const float*)d_in[3];
    const float* fc1_w = (const float*)d_in[4];
    const float* fc1_b = (const float*)d_in[5];
    const float* nn_v_w = (const float*)d_in[6];
    const float* nn_v_b = (const float*)d_in[7];
    const float* nn_c_w = (const float*)d_in[8];
    const float* nn_c_b = (const float*)d_in[9];
    const float* fc2_w = (const float*)d_in[10];
    const float* fc2_b = (const float*)d_in[11];
    float* out = (float*)d_out;

    const size_t SZ_XS = (size_t)NB * NN * NC;
    const size_t SZ_P = (size_t)NB * NN * NCOUT;
    const size_t BN = (size_t)NB * NN;
    const size_t SZ_CEN = (size_t)NB * NK * NC;
    const size_t SZ_PC = (size_t)NB * NK * NCOUT;

    float* base = (float*)d_ws;
    float* xs = base;                 // sorted fc1 out (fp32); reused as bf16 out_t later
    float* xpeRegion = xs + SZ_XS;    // bf16 conv out (ushort)
    float* Pb = xpeRegion + SZ_XS;    // bf16 PmQ (sorted) — no longer aliases D
    float* Qb = Pb + SZ_P;            // bf16 Qh (sorted)
    float* rinv = Qb + SZ_P;          // unused slot (layout stability)
    float* sqv = rinv + BN;
    float* cen = sqv + BN;            // unused (centroid in LDS), layout kept
    float* Pc = cen + SZ_CEN;
    float* Qc = Pc + SZ_PC;
    float* hcv = Qc + SZ_PC;
    int* order = (int*)(hcv + SZ_PC);
    int* mapping = order + BN;
    int* lsv = mapping + BN;
    int* nbrv = lsv + BN;
    int* cntk = nbrv + BN * KNB;
    int* offk = cntk + NB * NK;
    unsigned short* xpe = (unsigned short*)xpeRegion;
    unsigned short* PmQh = (unsigned short*)Pb;
    unsigned short* Qh = (unsigned short*)Qb;
    unsigned short* out_t = (unsigned short*)xs;  // xs fp32 dead after L3 (xe+cenpq)
    unsigned short* frag = (unsigned short*)(offk + NB * NK);
    unsigned short* hn_frag = frag;               // slot 0: hn fragments (hv -> fc2)
    unsigned short* xs_frag = frag + SZ_XS;
    unsigned short* wf1 = frag + 2 * SZ_XS;
    unsigned short* wfpmq = wf1 + (size_t)NC * NC;    // (Wtop-Wbot) 192x384
    unsigned short* wfq = wfpmq + (size_t)NC * NCOUT; // Wbot 192x384
    unsigned short* wf2 = wfq + (size_t)NC * NCOUT;
    _Float16* xef = (_Float16*)(wf2 + (size_t)NCOUT * NC);
    // D out of the Pb alias (enables pq || gram overlap). ~206MB total < 256MiB ws.
    float* Dbuf = (float*)(xef + (size_t)(NB * NK) * (20 * 6 * 512));

    // L1: conv | order | wcvt
    front_kernel<<<FRONT_CONV_BLOCKS + FRONT_ORDER_BLOCKS + FRONT_WCVT_BLOCKS, 256, 0, stream>>>(
        x, cpe_w, cpe_b, xpe, labels, order, mapping, lsv, cntk, offk, fc1_w, nn_v_w, fc2_w,
        wf1, wfpmq, wfq, wf2);
    // L2: fc1 fused with transpose
    fc1_kernel<<<NB * (NN / 64), 256, 0, stream>>>(xpe, wf1, fc1_b, xs, xs_frag, mapping);
    // L3: xe_cvt | cenpq (both depend only on xs)
    mid_kernel<<<MID_XE_BLOCKS + MID_CEN_BLOCKS, 384, 0, stream>>>(
        xs, offk, cntk, xef, sqv, nn_c_w, nn_c_b, Pc, Qc);
    // L4: pq GEMM | gram (independent; D un-aliased)
    knnpq_kernel<<<L4_PQ_BLOCKS + L4_GRAM_BLOCKS, 256, 0, stream>>>(
        xs_frag, wfpmq, wfq, nn_v_b, PmQh, Qh, xef, sqv, offk, cntk, Dbuf);
    // L5: select9 | hcmax
    sel_kernel<<<L5_SEL_BLOCKS + L5_HC_BLOCKS, 256, 0, stream>>>(
        Dbuf, lsv, offk, cntk, nbrv, Pc, Qc, hcv);
    // L6: hv wide-grid gather (R3 lesson: keep gather TLP)
    hv_kernel<<<dim3(NN / 4, NB), 192, 0, stream>>>(PmQh, Qh, nbrv, lsv, hcv, hn_frag);
    // L7: fc2 contiguous sorted rows
    gemm_mfma_hb<12><<<dim3(NC / 64, NN / 64, NB), 256, 0, stream>>>(
        hn_frag, SZ_P / NB, wf2, fc2_b, out_t, (size_t)NN * NC, NC);
    // L8: transpose + residual
    out_kernel<<<dim3(NC / 32, NN / 32, NB), dim3(32, 8), 0, stream>>>(out_t, x, mapping, out);
}